// Round 5
// baseline (767.749 us; speedup 1.0000x reference)
//
#include <hip/hip_runtime.h>

typedef __bf16 bf16x4 __attribute__((ext_vector_type(4)));
typedef __bf16 bf16x8 __attribute__((ext_vector_type(8)));
typedef float  f32x4  __attribute__((ext_vector_type(4)));

#define THREADS 256
constexpr int BK = 32, BKP = 40;

// ---- workspace layout (bytes), total <=160 MB ----
constexpr size_t MB = 1024*1024;
// persistent
constexpr size_t oH2    = 0;            // f32 [1024,2048] 8MB
constexpr size_t oXB2   = 8*MB;         // bf16 [1024,2048] 4MB
constexpr size_t oRT    = 12*MB;        // routing scratch (1MB)
// attention phase
constexpr size_t oWQKVT = 16*MB;        // bf16 hi [6144,2048] 24MB
constexpr size_t oWQKVL = 40*MB;        // bf16 lo 24MB
constexpr size_t oWOT   = 64*MB;        // bf16 hi [2048,2048] 8MB
constexpr size_t oWOL   = 72*MB;        // bf16 lo 8MB
constexpr size_t oXN1   = 80*MB;        // bf16 hi [1024,2048] 4MB
constexpr size_t oXN1L  = 84*MB;        // bf16 lo 4MB
constexpr size_t oQKV   = 88*MB;        // f32 [1024,6144] 24MB (dead after rope/VT)
constexpr size_t oSCF   = 112*MB;       // f32 [32,512,512] 32MB (dead after softmax)
constexpr size_t oQKS   = 144*MB;       // bf16 hi [1024,4096] 8MB (rotated q,k)
constexpr size_t oQKSL  = 152*MB;       // bf16 lo 8MB
// overlays (dead wqkvT after QKV gemm)
constexpr size_t oVT    = 16*MB;        // bf16 hi [32,128,512] 4MB
constexpr size_t oVTL   = 20*MB;        // bf16 lo 4MB
constexpr size_t oATT   = 24*MB;        // f32 [1024,2048] 8MB
constexpr size_t oPB    = 40*MB;        // bf16 hi [32,512,512] 16MB (over wqkv lo)
constexpr size_t oPBL2  = 88*MB;        // bf16 lo [32,512,512] 16MB (over dead qkv)
// MoE phase (after wo gemm everything 16..160 except none needed)
constexpr size_t oWGUT  = 16*MB;        // bf16 [8,2048,2048] 64MB
constexpr size_t oWDT   = 80*MB;        // bf16 [8,2048,1024] 32MB
constexpr size_t oSGUT  = 112*MB;       // bf16 [2048,2048] 8MB
constexpr size_t oSDT   = 120*MB;       // bf16 [2048,1024] 4MB
constexpr size_t oGU    = 124*MB;       // f32 [2048,2048] 16MB
constexpr size_t oHB    = 140*MB;       // bf16 [2048,1024] 4MB
constexpr size_t oY     = 144*MB;       // f32 [2048,2048] 16MB
constexpr size_t oSGU   = 16*MB;        // f32 [1024,2048] 8MB (wgut dead after routed-gu)
constexpr size_t oSHB   = 24*MB;        // bf16 [1024,1024] 2MB
constexpr size_t oSDB   = 26*MB;        // f32 [1024,2048] 8MB
// routing arrays
constexpr size_t oEIDX = oRT;
constexpr size_t oEW   = oRT + 8192;
constexpr size_t oSLOT = oRT + 16384;
constexpr size_t oLIST = oRT + 24576;
constexpr size_t oCNT  = oRT + 32768;
constexpr size_t oOFF  = oRT + 33024;
constexpr size_t oCUR  = oRT + 33280;

__device__ __forceinline__ bf16x8 bzero8() {
  bf16x8 z;
#pragma unroll
  for (int j = 0; j < 8; ++j) z[j] = (__bf16)0.f;
  return z;
}

// ---- 64x64 LDS tile transpose. OM: 1 = bf16 out, 2 = bf16 hi/lo planes ----
template<int OM>
__global__ void transpose_kernel(const float* __restrict__ in, __bf16* __restrict__ out,
                                 int ldin, int ldout, int zlo,
                                 long inBH, long inBL, long outB, long plane) {
  __shared__ float tile[64][65];
  int z = blockIdx.z;
  const float* inp = in + (long)(z / zlo) * inBH + (long)(z % zlo) * inBL;
  __bf16* outp = out + (long)z * outB;
  int r0 = blockIdx.y * 64, c0 = blockIdx.x * 64;
  int tid = threadIdx.x;
#pragma unroll
  for (int i = 0; i < 4; ++i) {
    int lin = tid + i * 256;
    int r = lin >> 4, c4 = (lin & 15) << 2;
    f32x4 v = *(const f32x4*)(inp + (long)(r0 + r) * ldin + c0 + c4);
    tile[r][c4] = v[0]; tile[r][c4+1] = v[1]; tile[r][c4+2] = v[2]; tile[r][c4+3] = v[3];
  }
  __syncthreads();
#pragma unroll
  for (int i = 0; i < 4; ++i) {
    int lin = tid + i * 256;
    int oR = lin >> 4, oC4 = (lin & 15) << 2;
    bf16x4 hi, lo;
#pragma unroll
    for (int j = 0; j < 4; ++j) {
      float v = tile[oC4 + j][oR];
      hi[j] = (__bf16)v;
      if constexpr (OM == 2) lo[j] = (__bf16)(v - (float)hi[j]);
    }
    __bf16* dst = outp + (long)(c0 + oR) * ldout + r0 + oC4;
    *(bf16x4*)dst = hi;
    if constexpr (OM == 2) *(bf16x4*)(dst + plane) = lo;
  }
}

// MODE 0: batched strided; MODE 1: gathered A rows; MODE 2: dense A rows at offsets
// SP 0: single bf16 A,B (1-term MFMA)
// SP 1: A f32 on-the-fly split, B pre-split bf16 planes (3-term)
// SP 2: A pre-split planes, B pre-split planes (3-term)
// Single-LDS-buffer, DEPTH-2 register pipeline: loads for tile k+2 are issued
// at the start of iter k and consumed by the LDS write at the end of iter k+1
// (coverage ~1 full K-step >= HBM latency). Two staging sets ping-pong with
// static indexing (explicit 2-phase loop body).
template<int MODE, int SP, bool RESID, bool CAUSAL, bool KTRI, int TBM = 128, int TBN = 128>
__global__ __launch_bounds__(256, 2)
void gemm_kernel(const void* __restrict__ Av, const void* __restrict__ Bv, float* __restrict__ C,
                 const float* __restrict__ Rres,
                 int M, int N, int K, int lda, int ldb, int ldc,
                 int zlo, long aHi, long aLo, long bHi, long bLo, long cHi, long cLo,
                 long aPlane, long bPlane,
                 const int* __restrict__ counts, const int* __restrict__ offsets,
                 const int* __restrict__ gather) {
  const int n0 = blockIdx.x * TBN;
  const int m0 = blockIdx.y * TBM;
  const int z  = blockIdx.z;
  if (CAUSAL && n0 > m0) return;   // fully-masked score tile

  const float*  Af = (const float*)Av;
  const __bf16* Ah = (const __bf16*)Av;
  const __bf16* Bh = (const __bf16*)Bv;

  int mcount; int rowbase = 0;
  long aoff = 0, boff = 0, coff = 0;
  if constexpr (MODE == 0) {
    mcount = M;
    int zh = z / zlo, zl = z % zlo;
    aoff = (long)zh*aHi + (long)zl*aLo;
    boff = (long)zh*bHi + (long)zl*bLo;
    coff = (long)zh*cHi + (long)zl*cLo;
  } else {
    mcount = counts[z];
    rowbase = offsets[z];
    if (m0 >= mcount) return;
    boff = (long)z*bHi;
  }

  constexpr bool TRI = (SP != 0);
  constexpr int ABUF = TBM*BKP;             // hi-plane size (elements)
  constexpr int BBUF = TBN*BKP;
  constexpr int WTM = TBM/2, WTN = TBN/2;   // per-wave tile
  constexpr int MI = WTM/16, MJ = WTN/16;   // 16x16 frags per wave
  __shared__ __align__(16) __bf16 As[(TRI?2:1)*ABUF];
  __shared__ __align__(16) __bf16 Bs[(TRI?2:1)*BBUF];

  const int tid = threadIdx.x;
  const int lane = tid & 63, wave = tid >> 6;
  const int wm = wave >> 1, wn = wave & 1;
  const int lq = lane >> 4, lr = lane & 15;

  int kend = K;
  if (KTRI) { int ke = m0 + TBM; kend = ke < K ? ke : K; }

  f32x4 acc[MI][MJ] = {};

  // ---- staging register sets (two, for depth-2 prefetch) ----
  constexpr int NAF = (SP==1) ? TBM/32 : 1;
  constexpr int NAH = (SP!=1) ? TBM/64 : 1;
  constexpr int NB  = TBN/64;
  constexpr int NAR = (SP==1) ? NAF : NAH;

  struct StageRegs {
    f32x4  arf[NAF];
    bf16x8 arh[NAH], arl[NAH];
    bf16x8 brh[NB],  brl[NB];
  };
  StageRegs s0, s1;

  // ---- hoisted per-thread row bases (constant across K) ----
  long aBase[NAR]; bool aOK[NAR];
#pragma unroll
  for (int it = 0; it < NAR; ++it) {
    int lin = tid + it*THREADS;
    int row = (SP==1) ? (lin >> 3) : (lin >> 2);
    int gr = m0 + row;
    aOK[it] = gr < mcount;
    long arow = 0;
    if (aOK[it]) {
      if constexpr (MODE == 1) arow = gather[rowbase + gr];
      else if constexpr (MODE == 2) arow = rowbase + gr;
      else arow = gr;
    }
    aBase[it] = aoff + arow*(long)lda;
  }
  long bBase[NB];
#pragma unroll
  for (int it = 0; it < NB; ++it) {
    int lin = tid + it*THREADS;
    int row = lin >> 2;
    bBase[it] = boff + (long)(n0+row)*ldb;
  }

  auto loadAB = [&](int kk, StageRegs& S) {
    if constexpr (SP == 1) {
#pragma unroll
      for (int it = 0; it < NAF; ++it) {
        int lin = tid + it*THREADS;
        int c4 = (lin & 7) << 2;
        f32x4 zv; zv[0]=0.f; zv[1]=0.f; zv[2]=0.f; zv[3]=0.f;
        S.arf[it] = aOK[it] ? *(const f32x4*)(Af + aBase[it] + kk + c4) : zv;
      }
    } else {
#pragma unroll
      for (int it = 0; it < NAH; ++it) {
        int lin = tid + it*THREADS;
        int c8 = (lin & 3) << 3;
        S.arh[it] = bzero8();
        if constexpr (SP == 2) S.arl[it] = bzero8();
        if (aOK[it]) {
          const __bf16* p = Ah + aBase[it] + kk + c8;
          S.arh[it] = *(const bf16x8*)p;
          if constexpr (SP == 2) S.arl[it] = *(const bf16x8*)(p + aPlane);
        }
      }
    }
#pragma unroll
    for (int it = 0; it < NB; ++it) {
      int lin = tid + it*THREADS;
      int c8 = (lin & 3) << 3;
      const __bf16* p = Bh + bBase[it] + kk + c8;
      S.brh[it] = *(const bf16x8*)p;
      if constexpr (TRI) S.brl[it] = *(const bf16x8*)(p + bPlane);
    }
  };

  auto writeAB = [&](const StageRegs& S) {
    if constexpr (SP == 1) {
#pragma unroll
      for (int it = 0; it < NAF; ++it) {
        int lin = tid + it*THREADS;
        int row = lin >> 3, c4 = (lin & 7) << 2;
        bf16x4 hi, lo;
#pragma unroll
        for (int j = 0; j < 4; ++j) {
          hi[j] = (__bf16)S.arf[it][j];
          lo[j] = (__bf16)(S.arf[it][j] - (float)hi[j]);
        }
        *(bf16x4*)(As + row*BKP + c4) = hi;
        *(bf16x4*)(As + ABUF + row*BKP + c4) = lo;
      }
    } else {
#pragma unroll
      for (int it = 0; it < NAH; ++it) {
        int lin = tid + it*THREADS;
        int row = lin >> 2, c8 = (lin & 3) << 3;
        *(bf16x8*)(As + row*BKP + c8) = S.arh[it];
        if constexpr (SP == 2) *(bf16x8*)(As + ABUF + row*BKP + c8) = S.arl[it];
      }
    }
#pragma unroll
    for (int it = 0; it < NB; ++it) {
      int lin = tid + it*THREADS;
      int row = lin >> 2, c8 = (lin & 3) << 3;
      *(bf16x8*)(Bs + row*BKP + c8) = S.brh[it];
      if constexpr (TRI) *(bf16x8*)(Bs + BBUF + row*BKP + c8) = S.brl[it];
    }
  };

  const __bf16* ap = As + (wm*WTM + lr)*BKP + lq*8;
  const __bf16* bp = Bs + (wn*WTN + lr)*BKP + lq*8;

  auto computeStep = [&]() {
    bf16x8 fa[MI], fal[MI];
#pragma unroll
    for (int i = 0; i < MI; ++i) {
      fa[i] = *(const bf16x8*)(ap + i*16*BKP);
      if constexpr (TRI) fal[i] = *(const bf16x8*)(ap + ABUF + i*16*BKP);
    }
#pragma unroll
    for (int j = 0; j < MJ; ++j) {
      bf16x8 fb = *(const bf16x8*)(bp + j*16*BKP);
      if constexpr (TRI) {
        bf16x8 fbl = *(const bf16x8*)(bp + BBUF + j*16*BKP);
#pragma unroll
        for (int i = 0; i < MI; ++i) {
          acc[i][j] = __builtin_amdgcn_mfma_f32_16x16x32_bf16(fa[i],  fbl, acc[i][j], 0, 0, 0);
          acc[i][j] = __builtin_amdgcn_mfma_f32_16x16x32_bf16(fal[i], fb,  acc[i][j], 0, 0, 0);
          acc[i][j] = __builtin_amdgcn_mfma_f32_16x16x32_bf16(fa[i],  fb,  acc[i][j], 0, 0, 0);
        }
      } else {
#pragma unroll
        for (int i = 0; i < MI; ++i)
          acc[i][j] = __builtin_amdgcn_mfma_f32_16x16x32_bf16(fa[i], fb, acc[i][j], 0, 0, 0);
      }
    }
  };

  // ---- prologue: tile 0 staged; tile 1 in flight ----
  loadAB(0, s0);
  writeAB(s0);
  __syncthreads();
  if (BK < kend) loadAB(BK, s1);

  // ---- depth-2 pipelined K loop (explicit 2-phase ping-pong) ----
  int k0 = 0;
  while (true) {
    // phase A: LDS holds tile k0; s1 holds tile k0+BK (in flight/landed)
    if (k0 + 2*BK < kend) loadAB(k0 + 2*BK, s0);
    computeStep();
    if (k0 + BK >= kend) break;
    __syncthreads();        // all waves done reading tile k0
    writeAB(s1);            // vmcnt waits only s1's loads (issued 1 iter ago)
    __syncthreads();
    k0 += BK;
    // phase B: LDS holds tile k0; s0 holds tile k0+BK
    if (k0 + 2*BK < kend) loadAB(k0 + 2*BK, s1);
    computeStep();
    if (k0 + BK >= kend) break;
    __syncthreads();
    writeAB(s0);
    __syncthreads();
    k0 += BK;
  }

  // epilogue: C/D layout col=lane&15, row=(lane>>4)*4+reg
#pragma unroll
  for (int i = 0; i < MI; ++i) {
#pragma unroll
    for (int rg = 0; rg < 4; ++rg) {
      int lrow = wm*WTM + i*16 + lq*4 + rg;
      int gr = m0 + lrow;
      if (gr < mcount) {
        long crow = coff + (long)(rowbase + gr)*ldc;
#pragma unroll
        for (int j = 0; j < MJ; ++j) {
          int col = n0 + wn*WTN + j*16 + lr;
          float val = acc[i][j][rg];
          if constexpr (RESID) val += Rres[(long)gr*ldc + col];
          C[crow + col] = val;
        }
      }
    }
  }
}

// OM 1: bf16 out; OM 2: bf16 hi/lo planes
template<int OM>
__global__ void rmsnorm_kernel(const float* __restrict__ x, const float* __restrict__ w,
                               __bf16* __restrict__ out, long plane) {
  const int row = blockIdx.x;
  const float* xr = x + (long)row * 2048;
  float ss = 0.f;
  for (int d = threadIdx.x; d < 2048; d += 256) { float v = xr[d]; ss += v*v; }
  __shared__ float red[4];
  int lane = threadIdx.x & 63, wave = threadIdx.x >> 6;
#pragma unroll
  for (int off = 32; off; off >>= 1) ss += __shfl_down(ss, off, 64);
  if (lane == 0) red[wave] = ss;
  __syncthreads();
  float tot = red[0] + red[1] + red[2] + red[3];
  float rs = rsqrtf(tot * (1.f/2048.f) + 1e-6f);
  __bf16* orow = out + (long)row * 2048;
  for (int d = threadIdx.x; d < 2048; d += 256) {
    float v = xr[d]*rs*w[d];
    __bf16 h = (__bf16)v;
    orow[d] = h;
    if constexpr (OM == 2) orow[d + plane] = (__bf16)(v - (float)h);
  }
}

// RoPE q,k from qkv f32 [1024,6144] -> rotated hi/lo bf16 [1024,4096] (q cols 0..2047, k 2048..4095)
__global__ void rope_split_kernel(const float* __restrict__ qkv, __bf16* __restrict__ o, long plane) {
  int tid = blockIdx.x*256 + threadIdx.x;   // 1024*16*64 threads
  int i = tid & 63;
  int th = tid >> 6;
  int h = th & 15;
  int t = th >> 4;
  int s = t & 511;
  long ib = (long)t*6144 + h*128;
  long ob = (long)t*4096 + h*128;
  float inv = 1.f / powf(10000.f, (float)i * (1.f/64.f));
  float ang = (float)s * inv;
  float c = cosf(ang), sn = sinf(ang);
  float q1 = qkv[ib+i], q2 = qkv[ib+64+i];
  float r1 = q1*c - q2*sn, r2 = q2*c + q1*sn;
  __bf16 h1 = (__bf16)r1, h2v = (__bf16)r2;
  o[ob+i] = h1;            o[ob+i+plane] = (__bf16)(r1 - (float)h1);
  o[ob+64+i] = h2v;        o[ob+64+i+plane] = (__bf16)(r2 - (float)h2v);
  float k1 = qkv[ib+2048+i], k2 = qkv[ib+2048+64+i];
  float s1 = k1*c - k2*sn, s2 = k2*c + k1*sn;
  __bf16 g1 = (__bf16)s1, g2 = (__bf16)s2;
  o[ob+2048+i] = g1;       o[ob+2048+i+plane] = (__bf16)(s1 - (float)g1);
  o[ob+2048+64+i] = g2;    o[ob+2048+64+i+plane] = (__bf16)(s2 - (float)g2);
}

// causal softmax: scf f32 -> P hi/lo bf16
__global__ void softmax_kernel(const float* __restrict__ sc, __bf16* __restrict__ p, long plane) {
  int r = blockIdx.x & 511;
  long bh = blockIdx.x >> 9;
  const float scale = 0.08838834764831845f;   // 1/sqrt(128)
  long base = (bh*512 + r)*512;
  int c0 = threadIdx.x, c1 = threadIdx.x + 256;
  float v0 = (c0 <= r) ? sc[base+c0]*scale : -3.0e38f;
  float v1 = (c1 <= r) ? sc[base+c1]*scale : -3.0e38f;
  float m = fmaxf(v0, v1);
  __shared__ float red[4];
  int lane = threadIdx.x & 63, wave = threadIdx.x >> 6;
#pragma unroll
  for (int off = 32; off; off >>= 1) m = fmaxf(m, __shfl_xor(m, off, 64));
  if (lane == 0) red[wave] = m;
  __syncthreads();
  m = fmaxf(fmaxf(red[0], red[1]), fmaxf(red[2], red[3]));
  __syncthreads();
  float e0 = (c0 <= r) ? expf(v0 - m) : 0.f;
  float e1 = (c1 <= r) ? expf(v1 - m) : 0.f;
  float s = e0 + e1;
#pragma unroll
  for (int off = 32; off; off >>= 1) s += __shfl_xor(s, off, 64);
  if (lane == 0) red[wave] = s;
  __syncthreads();
  s = red[0] + red[1] + red[2] + red[3];
  float inv = 1.f / s;
  float p0 = e0*inv, p1 = e1*inv;
  __bf16 h0 = (__bf16)p0, h1 = (__bf16)p1;
  p[base+c0] = h0; p[base+c0+plane] = (__bf16)(p0 - (float)h0);
  p[base+c1] = h1; p[base+c1+plane] = (__bf16)(p1 - (float)h1);
}

__global__ void zero8_kernel(int* c) { if (threadIdx.x < 8) c[threadIdx.x] = 0; }

__global__ void routing_kernel(const float* __restrict__ h2, const float* __restrict__ ln2w,
                               const float* __restrict__ gw, const float* __restrict__ gb,
                               int* __restrict__ eidx, float* __restrict__ ew,
                               int* __restrict__ counts) {
  int t = blockIdx.x;
  const float* xr = h2 + (long)t*2048;
  int lane = threadIdx.x & 63, wave = threadIdx.x >> 6;
  float ss = 0.f;
  for (int d = threadIdx.x; d < 2048; d += 256) { float v = xr[d]; ss += v*v; }
  __shared__ float red[4];
#pragma unroll
  for (int off = 32; off; off >>= 1) ss += __shfl_down(ss, off, 64);
  if (lane == 0) red[wave] = ss;
  __syncthreads();
  float rs = rsqrtf((red[0]+red[1]+red[2]+red[3]) * (1.f/2048.f) + 1e-6f);
  __shared__ float lg[8];
  for (int e = wave; e < 8; e += 4) {
    const float* wr = gw + (long)e*2048;
    float acc = 0.f;
    for (int d = lane; d < 2048; d += 64) acc += (xr[d]*rs*ln2w[d]) * wr[d];
#pragma unroll
    for (int off = 32; off; off >>= 1) acc += __shfl_down(acc, off, 64);
    if (lane == 0) lg[e] = acc;
  }
  __syncthreads();
  if (threadIdx.x == 0) {
    float sg[8], sc[8];
#pragma unroll
    for (int e = 0; e < 8; ++e) { sg[e] = 1.f/(1.f+expf(-lg[e])); sc[e] = sg[e] + gb[e]; }
    float gs[2];
#pragma unroll
    for (int g = 0; g < 2; ++g) {
      float m1 = -3e38f, m2 = -3e38f;
#pragma unroll
      for (int j = 0; j < 4; ++j) {
        float v = sc[4*g+j];
        if (v > m1) { m2 = m1; m1 = v; } else if (v > m2) m2 = v;
      }
      gs[g] = m1 + m2;
    }
    int b4 = (gs[1] > gs[0]) ? 4 : 0;
    int i1 = 0; float v1 = -3e38f;
#pragma unroll
    for (int j = 0; j < 4; ++j) if (sc[b4+j] > v1) { v1 = sc[b4+j]; i1 = j; }
    int i2 = -1; float v2 = -3e38f;
#pragma unroll
    for (int j = 0; j < 4; ++j) if (j != i1 && sc[b4+j] > v2) { v2 = sc[b4+j]; i2 = j; }
    float w1 = sg[b4+i1], w2 = sg[b4+i2], s = w1 + w2;
    eidx[t*2] = b4+i1; eidx[t*2+1] = b4+i2;
    ew[t*2] = w1/s;    ew[t*2+1] = w2/s;
    atomicAdd(&counts[b4+i1], 1); atomicAdd(&counts[b4+i2], 1);
  }
}

__global__ void scan_kernel(const int* __restrict__ counts, int* __restrict__ offsets,
                            int* __restrict__ cursors) {
  if (threadIdx.x == 0 && blockIdx.x == 0) {
    int s = 0;
    for (int e = 0; e < 8; ++e) { offsets[e] = s; s += counts[e]; cursors[e] = 0; }
    offsets[8] = s;
  }
}

__global__ void scatter_kernel(const int* __restrict__ eidx, const int* __restrict__ offsets,
                               int* __restrict__ cursors, int* __restrict__ list,
                               int* __restrict__ slot) {
  int t = blockIdx.x*256 + threadIdx.x;
  if (t < 1024) {
#pragma unroll
    for (int kk = 0; kk < 2; ++kk) {
      int e = eidx[t*2+kk];
      int pos = atomicAdd(&cursors[e], 1);
      int g = offsets[e] + pos;
      list[g] = t;
      slot[t*2+kk] = g;
    }
  }
}

// fused gate|up: gu[s][0:1024]=gate, gu[s][1024:2048]=up -> hb[s][0:1024]
__global__ void silumul_kernel(const float* __restrict__ gu, __bf16* __restrict__ o, int n) {
  int i = blockIdx.x*256 + threadIdx.x;
  if (i < n) {
    int s = i >> 10, j = i & 1023;
    float gv = gu[(long)s*2048 + j];
    float uv = gu[(long)s*2048 + 1024 + j];
    float sg = gv / (1.f + expf(-gv));
    o[i] = (__bf16)(sg * uv);
  }
}

__global__ void combine_kernel(const float* __restrict__ h2, const float* __restrict__ y,
                               const float* __restrict__ sdown, const int* __restrict__ slot,
                               const float* __restrict__ ew, float* __restrict__ out) {
  int i = blockIdx.x*256 + threadIdx.x;   // < 1024*2048
  int t = i >> 11;
  int d = i & 2047;
  float rv = ew[t*2]   * y[(long)slot[t*2]  *2048 + d]
           + ew[t*2+1] * y[(long)slot[t*2+1]*2048 + d];
  out[i] = h2[i] + sdown[i] + 2.5f * rv;
}

extern "C" void kernel_launch(void* const* d_in, const int* in_sizes, int n_in,
                              void* d_out, int out_size, void* d_ws, size_t ws_size,
                              hipStream_t stream) {
  const float* hid  = (const float*)d_in[0];
  const float* ln1  = (const float*)d_in[1];
  const float* ln2  = (const float*)d_in[2];
  const float* wq   = (const float*)d_in[3];
  const float* wk   = (const float*)d_in[4];
  const float* wv   = (const float*)d_in[5];
  const float* wo   = (const float*)d_in[6];
  const float* gw   = (const float*)d_in[7];
  const float* gb   = (const float*)d_in[8];
  const float* wgat = (const float*)d_in[9];
  const float* wup  = (const float*)d_in[10];
  const float* wdn  = (const float*)d_in[11];
  const float* swg  = (const float*)d_in[12];
  const float* swu  = (const float*)d_in[13];
  const float* swd  = (const float*)d_in[14];
  float* out = (float*)d_out;
  char* ws = (char*)d_ws;

  float*  h2    = (float*)(ws + oH2);
  __bf16* xb2   = (__bf16*)(ws + oXB2);
  __bf16* wqkvT = (__bf16*)(ws + oWQKVT);
  __bf16* woT   = (__bf16*)(ws + oWOT);
  __bf16* xn1   = (__bf16*)(ws + oXN1);
  float*  qkv   = (float*)(ws + oQKV);
  float*  scf   = (float*)(ws + oSCF);
  __bf16* qks   = (__bf16*)(ws + oQKS);
  __bf16* vtb   = (__bf16*)(ws + oVT);
  float*  att   = (float*)(ws + oATT);
  __bf16* pb    = (__bf16*)(ws + oPB);
  __bf16* wgut  = (__bf16*)(ws + oWGUT);
  __bf16* wdt   = (__bf16*)(ws + oWDT);
  __bf16* sgut  = (__bf16*)(ws + oSGUT);
  __bf16* sdt   = (__bf16*)(ws + oSDT);
  float*  gu    = (float*)(ws + oGU);
  __bf16* hb    = (__bf16*)(ws + oHB);
  float*  ybuf  = (float*)(ws + oY);
  float*  sgu   = (float*)(ws + oSGU);
  __bf16* shb   = (__bf16*)(ws + oSHB);
  float*  sdb   = (float*)(ws + oSDB);
  int*   eidx = (int*)(ws + oEIDX);
  float* ew   = (float*)(ws + oEW);
  int*   slot = (int*)(ws + oSLOT);
  int*   list = (int*)(ws + oLIST);
  int*   cnt  = (int*)(ws + oCNT);
  int*   offs = (int*)(ws + oOFF);
  int*   curs = (int*)(ws + oCUR);

  const long S22 = (long)2048*2048, S21 = (long)2048*1024;
  const long pWQKV = (oWQKVL - oWQKVT) / 2;   // 12,582,912 elements
  const long pWO   = (oWOL - oWOT) / 2;       // 4,194,304
  const long pXN1  = 2*MB;                    // 4MB/2B
  const long pQKS  = (oQKSL - oQKS) / 2;      // 4,194,304
  const long pVT   = 2*MB;
  const long pPB   = (oPBL2 - oPB) / 2;       // 48MB span /2B = 25,165,824

  // --- attention weight transposes: f32 [D,N] -> bf16 hi/lo [N,D] ---
  transpose_kernel<2><<<dim3(32,32,1), 256, 0, stream>>>(wq, wqkvT,          2048, 2048, 1, 0, 0, 0, pWQKV);
  transpose_kernel<2><<<dim3(32,32,1), 256, 0, stream>>>(wk, wqkvT + S22,    2048, 2048, 1, 0, 0, 0, pWQKV);
  transpose_kernel<2><<<dim3(32,32,1), 256, 0, stream>>>(wv, wqkvT + 2*S22,  2048, 2048, 1, 0, 0, 0, pWQKV);
  transpose_kernel<2><<<dim3(32,32,1), 256, 0, stream>>>(wo, woT,            2048, 2048, 1, 0, 0, 0, pWO);

  // --- attention ---
  rmsnorm_kernel<2><<<1024, 256, 0, stream>>>(hid, ln1, xn1, pXN1);

  // fused QKV: [1024,2048] x [6144,2048]^T -> qkv f32 [1024,6144]  (SP=2)
  gemm_kernel<0, 2, false, false, false, 64, 128><<<dim3(48,16,1), 256, 0, stream>>>(
      xn1, wqkvT, qkv, nullptr, 1024, 6144, 2048, 2048, 2048, 6144,
      1, 0, 0, 0, 0, 0, 0, pXN1, pWQKV, nullptr, nullptr, nullptr);

  // RoPE + split q,k -> qks hi/lo [1024,4096]
  rope_split_kernel<<<4096, 256, 0, stream>>>(qkv, qks, pQKS);

  // V^T per (b,h): qkv v-part [512,128] -> vtb hi/lo [32][128][512]
  transpose_kernel<2><<<dim3(2,8,32), 256, 0, stream>>>(
      qkv + 4096, vtb, 6144, 512, 16, (long)512*6144, 128, (long)128*512, pVT);

  // scores = Q @ K^T (SP=2, causal tile-skip) — 64x64 tiles
  gemm_kernel<0, 2, false, true, false, 64, 64><<<dim3(8,8,32), 256, 0, stream>>>(
      qks, qks + 2048, scf, nullptr, 512, 512, 128, 4096, 4096, 512,
      16, (long)512*4096, 128, (long)512*4096, 128, (long)16*512*512, (long)512*512,
      pQKS, pQKS, nullptr, nullptr, nullptr);

  // softmax -> P hi/lo
  softmax_kernel<<<16384, 256, 0, stream>>>(scf, pb, pPB);

  // attn = P @ V (SP=2, K-early-stop) — 64x64 tiles
  gemm_kernel<0, 2, false, false, true, 64, 64><<<dim3(2,8,32), 256, 0, stream>>>(
      pb, vtb, att, nullptr, 512, 128, 512, 512, 512, 2048,
      16, (long)16*512*512, (long)512*512, (long)16*128*512, (long)128*512,
      (long)512*2048, 128, pPB, pVT, nullptr, nullptr, nullptr);

  // h2 = hidden + attn @ wo  (SP=1) — 64x64 tiles
  gemm_kernel<0, 1, true, false, false, 64, 64><<<dim3(32,16,1), 256, 0, stream>>>(
      att, woT, h2, hid, 1024, 2048, 2048, 2048, 2048, 2048,
      1, 0, 0, 0, 0, 0, 0, 0, pWO, nullptr, nullptr, nullptr);

  // --- routing ---
  rmsnorm_kernel<1><<<1024, 256, 0, stream>>>(h2, ln2, xb2, 0);
  zero8_kernel<<<1, 64, 0, stream>>>(cnt);
  routing_kernel<<<1024, 256, 0, stream>>>(h2, ln2, gw, gb, eidx, ew, cnt);
  scan_kernel<<<1, 64, 0, stream>>>(cnt, offs, curs);
  scatter_kernel<<<4, 256, 0, stream>>>(eidx, offs, curs, list, slot);

  // --- MoE weight transposes (f32 -> bf16 single [N,K]) ---
  transpose_kernel<1><<<dim3(16,32,8), 256, 0, stream>>>(wgat, wgut,        1024, 2048, 1, S21, 0, S22, 0);
  transpose_kernel<1><<<dim3(16,32,8), 256, 0, stream>>>(wup,  wgut + S21,  1024, 2048, 1, S21, 0, S22, 0);
  transpose_kernel<1><<<dim3(32,16,8), 256, 0, stream>>>(wdn,  wdt,         2048, 1024, 1, S21, 0, S21, 0);
  transpose_kernel<1><<<dim3(16,32,1), 256, 0, stream>>>(swg,  sgut,        1024, 2048, 1, 0, 0, 0, 0);
  transpose_kernel<1><<<dim3(16,32,1), 256, 0, stream>>>(swu,  sgut + S21,  1024, 2048, 1, 0, 0, 0, 0);
  transpose_kernel<1><<<dim3(32,16,1), 256, 0, stream>>>(swd,  sdt,         2048, 1024, 1, 0, 0, 0, 0);

  // --- routed experts: fused gate|up then down --- 64x64 tiles
  gemm_kernel<1, 0, false, false, false, 64, 64><<<dim3(32,16,8), 256, 0, stream>>>(
      xb2, wgut, gu, nullptr, 1024, 2048, 2048, 2048, 2048, 2048,
      1, 0, 0, S22, 0, 0, 0, 0, 0, cnt, offs, list);
  silumul_kernel<<<8192, 256, 0, stream>>>(gu, hb, 2048*1024);
  gemm_kernel<2, 0, false, false, false, 64, 64><<<dim3(32,16,8), 256, 0, stream>>>(
      hb, wdt, ybuf, nullptr, 1024, 2048, 1024, 1024, 1024, 2048,
      1, 0, 0, S21, 0, 0, 0, 0, 0, cnt, offs, nullptr);

  // --- shared expert --- 64x64 tiles
  gemm_kernel<0, 0, false, false, false, 64, 64><<<dim3(32,16,1), 256, 0, stream>>>(
      xb2, sgut, sgu, nullptr, 1024, 2048, 2048, 2048, 2048, 2048,
      1, 0, 0, 0, 0, 0, 0, 0, 0, nullptr, nullptr, nullptr);
  silumul_kernel<<<4096, 256, 0, stream>>>(sgu, shb, 1024*1024);
  gemm_kernel<0, 0, false, false, false, 64, 64><<<dim3(32,16,1), 256, 0, stream>>>(
      shb, sdt, sdb, nullptr, 1024, 2048, 1024, 1024, 1024, 2048,
      1, 0, 0, 0, 0, 0, 0, 0, 0, nullptr, nullptr, nullptr);

  // --- combine ---
  combine_kernel<<<8192, 256, 0, stream>>>(h2, ybuf, sdb, slot, ew, out);
}

// Round 6
// 706.051 us; speedup vs baseline: 1.0874x; 1.0874x over previous
//
#include <hip/hip_runtime.h>

typedef __bf16 bf16x4 __attribute__((ext_vector_type(4)));
typedef __bf16 bf16x8 __attribute__((ext_vector_type(8)));
typedef _Float16 f16x4 __attribute__((ext_vector_type(4)));
typedef _Float16 f16x8 __attribute__((ext_vector_type(8)));
typedef float  f32x4  __attribute__((ext_vector_type(4)));

#define THREADS 256
constexpr int BK = 32, BKP = 40;

// ---- workspace layout (bytes), total <=160 MB ----
constexpr size_t MB = 1024*1024;
// persistent
constexpr size_t oH2    = 0;            // f32 [1024,2048] 8MB
constexpr size_t oXB2   = 8*MB;         // bf16 [1024,2048] 4MB
constexpr size_t oRT    = 12*MB;        // routing scratch (1MB)
// attention phase
constexpr size_t oWQKVT = 16*MB;        // f16 [6144,2048] 24MB (single plane now)
constexpr size_t oWOT   = 64*MB;        // f16 [2048,2048] 8MB
constexpr size_t oXN1   = 80*MB;        // f16 [1024,2048] 4MB
constexpr size_t oQKV   = 88*MB;        // f32 [1024,6144] 24MB (dead after rope/VT)
constexpr size_t oSCF   = 112*MB;       // f32 [32,512,512] 32MB (dead after softmax)
constexpr size_t oQKS   = 144*MB;       // bf16 hi [1024,4096] 8MB (rotated q,k)
constexpr size_t oQKSL  = 152*MB;       // bf16 lo 8MB
// overlays (dead wqkvT after QKV gemm)
constexpr size_t oVT    = 16*MB;        // bf16 hi [32,128,512] 4MB
constexpr size_t oVTL   = 20*MB;        // bf16 lo 4MB
constexpr size_t oATT   = 24*MB;        // f32 [1024,2048] 8MB
constexpr size_t oPB    = 40*MB;        // bf16 hi [32,512,512] 16MB
constexpr size_t oPBL2  = 88*MB;        // bf16 lo [32,512,512] 16MB (over dead qkv)
// MoE phase
constexpr size_t oWGUT  = 16*MB;        // bf16 [8,2048,2048] 64MB
constexpr size_t oWDT   = 80*MB;        // bf16 [8,2048,1024] 32MB
constexpr size_t oSGUT  = 112*MB;       // bf16 [2048,2048] 8MB
constexpr size_t oSDT   = 120*MB;       // bf16 [2048,1024] 4MB
constexpr size_t oHB    = 140*MB;       // bf16 [2048,1024] 4MB
constexpr size_t oY     = 144*MB;       // f32 [2048,2048] 16MB
constexpr size_t oSHB   = 24*MB;        // bf16 [1024,1024] 2MB (over dead att)
constexpr size_t oSDB   = 26*MB;        // f32 [1024,2048] 8MB
// routing arrays
constexpr size_t oEIDX = oRT;
constexpr size_t oEW   = oRT + 8192;
constexpr size_t oSLOT = oRT + 16384;
constexpr size_t oLIST = oRT + 24576;
constexpr size_t oCNT  = oRT + 32768;
constexpr size_t oOFF  = oRT + 33024;
constexpr size_t oCUR  = oRT + 33280;

__device__ __forceinline__ bf16x8 bzero8() {
  bf16x8 z;
#pragma unroll
  for (int j = 0; j < 8; ++j) z[j] = (__bf16)0.f;
  return z;
}

// ---- 64x64 LDS tile transpose. OM: 1 = bf16, 2 = bf16 hi/lo planes, 3 = f16 ----
template<int OM>
__global__ void transpose_kernel(const float* __restrict__ in, __bf16* __restrict__ out,
                                 int ldin, int ldout, int zlo,
                                 long inBH, long inBL, long outB, long plane) {
  __shared__ float tile[64][65];
  int z = blockIdx.z;
  const float* inp = in + (long)(z / zlo) * inBH + (long)(z % zlo) * inBL;
  __bf16* outp = out + (long)z * outB;
  int r0 = blockIdx.y * 64, c0 = blockIdx.x * 64;
  int tid = threadIdx.x;
#pragma unroll
  for (int i = 0; i < 4; ++i) {
    int lin = tid + i * 256;
    int r = lin >> 4, c4 = (lin & 15) << 2;
    f32x4 v = *(const f32x4*)(inp + (long)(r0 + r) * ldin + c0 + c4);
    tile[r][c4] = v[0]; tile[r][c4+1] = v[1]; tile[r][c4+2] = v[2]; tile[r][c4+3] = v[3];
  }
  __syncthreads();
#pragma unroll
  for (int i = 0; i < 4; ++i) {
    int lin = tid + i * 256;
    int oR = lin >> 4, oC4 = (lin & 15) << 2;
    __bf16* dst = outp + (long)(c0 + oR) * ldout + r0 + oC4;
    if constexpr (OM == 3) {
      f16x4 hv;
#pragma unroll
      for (int j = 0; j < 4; ++j) hv[j] = (_Float16)tile[oC4 + j][oR];
      *reinterpret_cast<f16x4*>(dst) = hv;
    } else {
      bf16x4 hi, lo;
#pragma unroll
      for (int j = 0; j < 4; ++j) {
        float v = tile[oC4 + j][oR];
        hi[j] = (__bf16)v;
        if constexpr (OM == 2) lo[j] = (__bf16)(v - (float)hi[j]);
      }
      *(bf16x4*)dst = hi;
      if constexpr (OM == 2) *(bf16x4*)(dst + plane) = lo;
    }
  }
}

// MODE 0: batched strided; MODE 1: gathered A rows; MODE 2: dense A rows at offsets
// SP 0: single bf16 A,B (1-term)
// SP 1: A f32 on-the-fly bf16 split, B pre-split planes (3-term)
// SP 2: A pre-split planes, B pre-split planes (3-term)
// SP 3: single f16 A,B (1-term f16 MFMA)
// SP 4: A f32 on-the-fly -> f16, B f16 (1-term f16 MFMA)
// Single-LDS-buffer issue-early/write-late pipeline (T14).
template<int MODE, int SP, bool RESID, bool CAUSAL, bool KTRI, int TBM = 128, int TBN = 128>
__global__ __launch_bounds__(256, 2)
void gemm_kernel(const void* __restrict__ Av, const void* __restrict__ Bv, float* __restrict__ C,
                 const float* __restrict__ Rres,
                 int M, int N, int K, int lda, int ldb, int ldc,
                 int zlo, long aHi, long aLo, long bHi, long bLo, long cHi, long cLo,
                 long aPlane, long bPlane,
                 const int* __restrict__ counts, const int* __restrict__ offsets,
                 const int* __restrict__ gather) {
  const int n0 = blockIdx.x * TBN;
  const int m0 = blockIdx.y * TBM;
  const int z  = blockIdx.z;
  if (CAUSAL && n0 > m0) return;

  const float*  Af = (const float*)Av;
  const __bf16* Ah = (const __bf16*)Av;
  const __bf16* Bh = (const __bf16*)Bv;

  int mcount; int rowbase = 0;
  long aoff = 0, boff = 0, coff = 0;
  if constexpr (MODE == 0) {
    mcount = M;
    int zh = z / zlo, zl = z % zlo;
    aoff = (long)zh*aHi + (long)zl*aLo;
    boff = (long)zh*bHi + (long)zl*bLo;
    coff = (long)zh*cHi + (long)zl*cLo;
  } else {
    mcount = counts[z];
    rowbase = offsets[z];
    if (m0 >= mcount) return;
    boff = (long)z*bHi;
  }

  constexpr bool TRI  = (SP == 1 || SP == 2);   // 3-term bf16 split
  constexpr bool F16  = (SP == 3 || SP == 4);   // f16 single
  constexpr bool AFLY = (SP == 1 || SP == 4);   // A loaded as f32, converted at LDS-write
  constexpr int ABUF = TBM*BKP;
  constexpr int BBUF = TBN*BKP;
  constexpr int WTM = TBM/2, WTN = TBN/2;
  constexpr int MI = WTM/16, MJ = WTN/16;
  __shared__ __align__(16) __bf16 As[(TRI?2:1)*ABUF];
  __shared__ __align__(16) __bf16 Bs[(TRI?2:1)*BBUF];

  const int tid = threadIdx.x;
  const int lane = tid & 63, wave = tid >> 6;
  const int wm = wave >> 1, wn = wave & 1;
  const int lq = lane >> 4, lr = lane & 15;

  int kend = K;
  if (KTRI) { int ke = m0 + TBM; kend = ke < K ? ke : K; }

  f32x4 acc[MI][MJ] = {};

  constexpr int NAF = AFLY ? TBM/32 : 1;
  constexpr int NAH = (!AFLY) ? TBM/64 : 1;
  constexpr int NB  = TBN/64;
  f32x4  arf[NAF];
  bf16x8 arh[NAH], arl[NAH];
  bf16x8 brh[NB],  brl[NB];

  auto loadAB = [&](int kk) {
    if constexpr (AFLY) {
#pragma unroll
      for (int it = 0; it < NAF; ++it) {
        int lin = tid + it*THREADS;
        int row = lin >> 3, c4 = (lin & 7) << 2;
        int gr = m0 + row;
        f32x4 zv; zv[0]=0.f; zv[1]=0.f; zv[2]=0.f; zv[3]=0.f;
        arf[it] = (gr < mcount) ? *(const f32x4*)(Af + aoff + (long)gr*lda + kk + c4) : zv;
      }
    } else {
#pragma unroll
      for (int it = 0; it < NAH; ++it) {
        int lin = tid + it*THREADS;
        int row = lin >> 2, c8 = (lin & 3) << 3;
        int gr = m0 + row;
        arh[it] = bzero8();
        if constexpr (SP == 2) arl[it] = bzero8();
        if (gr < mcount) {
          long arow;
          if constexpr (MODE == 1) arow = gather[rowbase + gr];
          else if constexpr (MODE == 2) arow = rowbase + gr;
          else arow = gr;
          const __bf16* p = Ah + aoff + arow*(long)lda + kk + c8;
          arh[it] = *(const bf16x8*)p;
          if constexpr (SP == 2) arl[it] = *(const bf16x8*)(p + aPlane);
        }
      }
    }
#pragma unroll
    for (int it = 0; it < NB; ++it) {
      int lin = tid + it*THREADS;
      int row = lin >> 2, c8 = (lin & 3) << 3;
      const __bf16* p = Bh + boff + (long)(n0+row)*ldb + kk + c8;
      brh[it] = *(const bf16x8*)p;
      if constexpr (TRI) brl[it] = *(const bf16x8*)(p + bPlane);
    }
  };

  auto writeAB = [&]() {
    if constexpr (AFLY) {
#pragma unroll
      for (int it = 0; it < NAF; ++it) {
        int lin = tid + it*THREADS;
        int row = lin >> 3, c4 = (lin & 7) << 2;
        if constexpr (SP == 4) {
          f16x4 hv;
#pragma unroll
          for (int j = 0; j < 4; ++j) hv[j] = (_Float16)arf[it][j];
          *reinterpret_cast<f16x4*>(As + row*BKP + c4) = hv;
        } else {
          bf16x4 hi, lo;
#pragma unroll
          for (int j = 0; j < 4; ++j) {
            hi[j] = (__bf16)arf[it][j];
            lo[j] = (__bf16)(arf[it][j] - (float)hi[j]);
          }
          *(bf16x4*)(As + row*BKP + c4) = hi;
          *(bf16x4*)(As + ABUF + row*BKP + c4) = lo;
        }
      }
    } else {
#pragma unroll
      for (int it = 0; it < NAH; ++it) {
        int lin = tid + it*THREADS;
        int row = lin >> 2, c8 = (lin & 3) << 3;
        *(bf16x8*)(As + row*BKP + c8) = arh[it];
        if constexpr (SP == 2) *(bf16x8*)(As + ABUF + row*BKP + c8) = arl[it];
      }
    }
#pragma unroll
    for (int it = 0; it < NB; ++it) {
      int lin = tid + it*THREADS;
      int row = lin >> 2, c8 = (lin & 3) << 3;
      *(bf16x8*)(Bs + row*BKP + c8) = brh[it];
      if constexpr (TRI) *(bf16x8*)(Bs + BBUF + row*BKP + c8) = brl[it];
    }
  };

  loadAB(0);
  writeAB();
  __syncthreads();

  for (int k0 = 0; k0 < kend; k0 += BK) {
    const bool hn = (k0 + BK < kend);
    if (hn) loadAB(k0 + BK);

    const __bf16* ap = As + (wm*WTM + lr)*BKP + lq*8;
    const __bf16* bp = Bs + (wn*WTN + lr)*BKP + lq*8;
    if constexpr (F16) {
      f16x8 fa[MI];
#pragma unroll
      for (int i = 0; i < MI; ++i)
        fa[i] = *reinterpret_cast<const f16x8*>(ap + i*16*BKP);
#pragma unroll
      for (int j = 0; j < MJ; ++j) {
        f16x8 fb = *reinterpret_cast<const f16x8*>(bp + j*16*BKP);
#pragma unroll
        for (int i = 0; i < MI; ++i)
          acc[i][j] = __builtin_amdgcn_mfma_f32_16x16x32_f16(fa[i], fb, acc[i][j], 0, 0, 0);
      }
    } else {
      bf16x8 fa[MI], fal[MI];
#pragma unroll
      for (int i = 0; i < MI; ++i) {
        fa[i] = *(const bf16x8*)(ap + i*16*BKP);
        if constexpr (TRI) fal[i] = *(const bf16x8*)(ap + ABUF + i*16*BKP);
      }
#pragma unroll
      for (int j = 0; j < MJ; ++j) {
        bf16x8 fb = *(const bf16x8*)(bp + j*16*BKP);
        if constexpr (TRI) {
          bf16x8 fbl = *(const bf16x8*)(bp + BBUF + j*16*BKP);
#pragma unroll
          for (int i = 0; i < MI; ++i) {
            acc[i][j] = __builtin_amdgcn_mfma_f32_16x16x32_bf16(fa[i],  fbl, acc[i][j], 0, 0, 0);
            acc[i][j] = __builtin_amdgcn_mfma_f32_16x16x32_bf16(fal[i], fb,  acc[i][j], 0, 0, 0);
            acc[i][j] = __builtin_amdgcn_mfma_f32_16x16x32_bf16(fa[i],  fb,  acc[i][j], 0, 0, 0);
          }
        } else {
#pragma unroll
          for (int i = 0; i < MI; ++i)
            acc[i][j] = __builtin_amdgcn_mfma_f32_16x16x32_bf16(fa[i], fb, acc[i][j], 0, 0, 0);
        }
      }
    }

    if (hn) {
      __syncthreads();
      writeAB();
      __syncthreads();
    }
  }

  // epilogue: C/D layout col=lane&15, row=(lane>>4)*4+reg
#pragma unroll
  for (int i = 0; i < MI; ++i) {
#pragma unroll
    for (int rg = 0; rg < 4; ++rg) {
      int lrow = wm*WTM + i*16 + lq*4 + rg;
      int gr = m0 + lrow;
      if (gr < mcount) {
        long crow = coff + (long)(rowbase + gr)*ldc;
#pragma unroll
        for (int j = 0; j < MJ; ++j) {
          int col = n0 + wn*WTN + j*16 + lr;
          float val = acc[i][j][rg];
          if constexpr (RESID) val += Rres[(long)gr*ldc + col];
          C[crow + col] = val;
        }
      }
    }
  }
}

// Fused gate/up gemm + silu*mul epilogue. bf16 A [*,2048], B [z][2048,2048]
// (rows 0..1023 gate^T, 1024..2047 up^T). Out bf16 [rows,1024].
// MODE 0: dense A rows; MODE 1: gathered A rows.
template<int MODE>
__global__ __launch_bounds__(256, 2)
void gugemm_kernel(const __bf16* __restrict__ A, const __bf16* __restrict__ B,
                   __bf16* __restrict__ O, int M, int K, int lda, int ldb, long bHi,
                   const int* __restrict__ counts, const int* __restrict__ offsets,
                   const int* __restrict__ gather) {
  const int n0 = blockIdx.x * 64;
  const int m0 = blockIdx.y * 64;
  const int z  = blockIdx.z;

  int mcount; int rowbase = 0; long boff = 0;
  if constexpr (MODE == 1) {
    mcount = counts[z];
    rowbase = offsets[z];
    if (m0 >= mcount) return;
    boff = (long)z*bHi;
  } else {
    mcount = M;
  }

  constexpr int TBUF = 64*BKP;
  __shared__ __align__(16) __bf16 As[TBUF];
  __shared__ __align__(16) __bf16 Bg[TBUF];
  __shared__ __align__(16) __bf16 Bu[TBUF];

  const int tid = threadIdx.x;
  const int lane = tid & 63, wave = tid >> 6;
  const int wm = wave >> 1, wn = wave & 1;
  const int lq = lane >> 4, lr = lane & 15;

  f32x4 accG[2][2] = {}, accU[2][2] = {};

  // staging regs
  bf16x8 ar, bg, bu;
  const int srow = tid >> 2, sc8 = (tid & 3) << 3;
  long aBase; bool aOK;
  {
    int gr = m0 + srow;
    aOK = gr < mcount;
    long arow = 0;
    if (aOK) {
      if constexpr (MODE == 1) arow = gather[rowbase + gr];
      else arow = gr;
    }
    aBase = arow*(long)lda;
  }
  const long gBase = boff + (long)(n0 + srow)*ldb;
  const long uBase = boff + (long)(1024 + n0 + srow)*ldb;

  auto loadAB = [&](int kk) {
    ar = aOK ? *(const bf16x8*)(A + aBase + kk + sc8) : bzero8();
    bg = *(const bf16x8*)(B + gBase + kk + sc8);
    bu = *(const bf16x8*)(B + uBase + kk + sc8);
  };
  auto writeAB = [&]() {
    *(bf16x8*)(As + srow*BKP + sc8) = ar;
    *(bf16x8*)(Bg + srow*BKP + sc8) = bg;
    *(bf16x8*)(Bu + srow*BKP + sc8) = bu;
  };

  loadAB(0);
  writeAB();
  __syncthreads();

  for (int k0 = 0; k0 < K; k0 += BK) {
    const bool hn = (k0 + BK < K);
    if (hn) loadAB(k0 + BK);

    const __bf16* ap  = As + (wm*32 + lr)*BKP + lq*8;
    const __bf16* bgp = Bg + (wn*32 + lr)*BKP + lq*8;
    const __bf16* bup = Bu + (wn*32 + lr)*BKP + lq*8;
    bf16x8 fa[2];
    fa[0] = *(const bf16x8*)(ap);
    fa[1] = *(const bf16x8*)(ap + 16*BKP);
#pragma unroll
    for (int j = 0; j < 2; ++j) {
      bf16x8 fg = *(const bf16x8*)(bgp + j*16*BKP);
      bf16x8 fu = *(const bf16x8*)(bup + j*16*BKP);
#pragma unroll
      for (int i = 0; i < 2; ++i) {
        accG[i][j] = __builtin_amdgcn_mfma_f32_16x16x32_bf16(fa[i], fg, accG[i][j], 0, 0, 0);
        accU[i][j] = __builtin_amdgcn_mfma_f32_16x16x32_bf16(fa[i], fu, accU[i][j], 0, 0, 0);
      }
    }

    if (hn) {
      __syncthreads();
      writeAB();
      __syncthreads();
    }
  }

  // epilogue: silu(gate)*up -> bf16
#pragma unroll
  for (int i = 0; i < 2; ++i) {
#pragma unroll
    for (int rg = 0; rg < 4; ++rg) {
      int lrow = wm*32 + i*16 + lq*4 + rg;
      int gr = m0 + lrow;
      if (gr < mcount) {
        long orow = (long)(rowbase + gr)*1024;
#pragma unroll
        for (int j = 0; j < 2; ++j) {
          int col = n0 + wn*32 + j*16 + lr;
          float g = accG[i][j][rg], u = accU[i][j][rg];
          float val = (g / (1.f + expf(-g))) * u;
          O[orow + col] = (__bf16)val;
        }
      }
    }
  }
}

// OM 1: bf16 out; OM 2: bf16 hi/lo planes; OM 3: f16 out
template<int OM>
__global__ void rmsnorm_kernel(const float* __restrict__ x, const float* __restrict__ w,
                               __bf16* __restrict__ out, long plane) {
  const int row = blockIdx.x;
  const float* xr = x + (long)row * 2048;
  float ss = 0.f;
  for (int d = threadIdx.x; d < 2048; d += 256) { float v = xr[d]; ss += v*v; }
  __shared__ float red[4];
  int lane = threadIdx.x & 63, wave = threadIdx.x >> 6;
#pragma unroll
  for (int off = 32; off; off >>= 1) ss += __shfl_down(ss, off, 64);
  if (lane == 0) red[wave] = ss;
  __syncthreads();
  float tot = red[0] + red[1] + red[2] + red[3];
  float rs = rsqrtf(tot * (1.f/2048.f) + 1e-6f);
  __bf16* orow = out + (long)row * 2048;
  for (int d = threadIdx.x; d < 2048; d += 256) {
    float v = xr[d]*rs*w[d];
    if constexpr (OM == 3) {
      ((_Float16*)orow)[d] = (_Float16)v;
    } else {
      __bf16 h = (__bf16)v;
      orow[d] = h;
      if constexpr (OM == 2) orow[d + plane] = (__bf16)(v - (float)h);
    }
  }
}

// RoPE q,k from qkv f32 [1024,6144] -> rotated hi/lo bf16 [1024,4096]
__global__ void rope_split_kernel(const float* __restrict__ qkv, __bf16* __restrict__ o, long plane) {
  int tid = blockIdx.x*256 + threadIdx.x;
  int i = tid & 63;
  int th = tid >> 6;
  int h = th & 15;
  int t = th >> 4;
  int s = t & 511;
  long ib = (long)t*6144 + h*128;
  long ob = (long)t*4096 + h*128;
  float inv = 1.f / powf(10000.f, (float)i * (1.f/64.f));
  float ang = (float)s * inv;
  float c = cosf(ang), sn = sinf(ang);
  float q1 = qkv[ib+i], q2 = qkv[ib+64+i];
  float r1 = q1*c - q2*sn, r2 = q2*c + q1*sn;
  __bf16 h1 = (__bf16)r1, h2v = (__bf16)r2;
  o[ob+i] = h1;            o[ob+i+plane] = (__bf16)(r1 - (float)h1);
  o[ob+64+i] = h2v;        o[ob+64+i+plane] = (__bf16)(r2 - (float)h2v);
  float k1 = qkv[ib+2048+i], k2 = qkv[ib+2048+64+i];
  float s1 = k1*c - k2*sn, s2 = k2*c + k1*sn;
  __bf16 g1 = (__bf16)s1, g2 = (__bf16)s2;
  o[ob+2048+i] = g1;       o[ob+2048+i+plane] = (__bf16)(s1 - (float)g1);
  o[ob+2048+64+i] = g2;    o[ob+2048+64+i+plane] = (__bf16)(s2 - (float)g2);
}

// causal softmax: scf f32 -> P hi/lo bf16
__global__ void softmax_kernel(const float* __restrict__ sc, __bf16* __restrict__ p, long plane) {
  int r = blockIdx.x & 511;
  long bh = blockIdx.x >> 9;
  const float scale = 0.08838834764831845f;   // 1/sqrt(128)
  long base = (bh*512 + r)*512;
  int c0 = threadIdx.x, c1 = threadIdx.x + 256;
  float v0 = (c0 <= r) ? sc[base+c0]*scale : -3.0e38f;
  float v1 = (c1 <= r) ? sc[base+c1]*scale : -3.0e38f;
  float m = fmaxf(v0, v1);
  __shared__ float red[4];
  int lane = threadIdx.x & 63, wave = threadIdx.x >> 6;
#pragma unroll
  for (int off = 32; off; off >>= 1) m = fmaxf(m, __shfl_xor(m, off, 64));
  if (lane == 0) red[wave] = m;
  __syncthreads();
  m = fmaxf(fmaxf(red[0], red[1]), fmaxf(red[2], red[3]));
  __syncthreads();
  float e0 = (c0 <= r) ? expf(v0 - m) : 0.f;
  float e1 = (c1 <= r) ? expf(v1 - m) : 0.f;
  float s = e0 + e1;
#pragma unroll
  for (int off = 32; off; off >>= 1) s += __shfl_xor(s, off, 64);
  if (lane == 0) red[wave] = s;
  __syncthreads();
  s = red[0] + red[1] + red[2] + red[3];
  float inv = 1.f / s;
  float p0 = e0*inv, p1 = e1*inv;
  __bf16 h0 = (__bf16)p0, h1 = (__bf16)p1;
  p[base+c0] = h0; p[base+c0+plane] = (__bf16)(p0 - (float)h0);
  p[base+c1] = h1; p[base+c1+plane] = (__bf16)(p1 - (float)h1);
}

__global__ void zero8_kernel(int* c) { if (threadIdx.x < 8) c[threadIdx.x] = 0; }

// routing + fused rmsnorm2 (writes xb2)
__global__ void routing_kernel(const float* __restrict__ h2, const float* __restrict__ ln2w,
                               const float* __restrict__ gw, const float* __restrict__ gb,
                               __bf16* __restrict__ xb2,
                               int* __restrict__ eidx, float* __restrict__ ew,
                               int* __restrict__ counts) {
  int t = blockIdx.x;
  const float* xr = h2 + (long)t*2048;
  int lane = threadIdx.x & 63, wave = threadIdx.x >> 6;
  float ss = 0.f;
  for (int d = threadIdx.x; d < 2048; d += 256) { float v = xr[d]; ss += v*v; }
  __shared__ float red[4];
#pragma unroll
  for (int off = 32; off; off >>= 1) ss += __shfl_down(ss, off, 64);
  if (lane == 0) red[wave] = ss;
  __syncthreads();
  float rs = rsqrtf((red[0]+red[1]+red[2]+red[3]) * (1.f/2048.f) + 1e-6f);
  // fused rmsnorm output
  __bf16* xrow = xb2 + (long)t*2048;
  for (int d = threadIdx.x; d < 2048; d += 256) xrow[d] = (__bf16)(xr[d]*rs*ln2w[d]);
  __shared__ float lg[8];
  for (int e = wave; e < 8; e += 4) {
    const float* wr = gw + (long)e*2048;
    float acc = 0.f;
    for (int d = lane; d < 2048; d += 64) acc += (xr[d]*rs*ln2w[d]) * wr[d];
#pragma unroll
    for (int off = 32; off; off >>= 1) acc += __shfl_down(acc, off, 64);
    if (lane == 0) lg[e] = acc;
  }
  __syncthreads();
  if (threadIdx.x == 0) {
    float sg[8], sc[8];
#pragma unroll
    for (int e = 0; e < 8; ++e) { sg[e] = 1.f/(1.f+expf(-lg[e])); sc[e] = sg[e] + gb[e]; }
    float gs[2];
#pragma unroll
    for (int g = 0; g < 2; ++g) {
      float m1 = -3e38f, m2 = -3e38f;
#pragma unroll
      for (int j = 0; j < 4; ++j) {
        float v = sc[4*g+j];
        if (v > m1) { m2 = m1; m1 = v; } else if (v > m2) m2 = v;
      }
      gs[g] = m1 + m2;
    }
    int b4 = (gs[1] > gs[0]) ? 4 : 0;
    int i1 = 0; float v1 = -3e38f;
#pragma unroll
    for (int j = 0; j < 4; ++j) if (sc[b4+j] > v1) { v1 = sc[b4+j]; i1 = j; }
    int i2 = -1; float v2 = -3e38f;
#pragma unroll
    for (int j = 0; j < 4; ++j) if (j != i1 && sc[b4+j] > v2) { v2 = sc[b4+j]; i2 = j; }
    float w1 = sg[b4+i1], w2 = sg[b4+i2], s = w1 + w2;
    eidx[t*2] = b4+i1; eidx[t*2+1] = b4+i2;
    ew[t*2] = w1/s;    ew[t*2+1] = w2/s;
    atomicAdd(&counts[b4+i1], 1); atomicAdd(&counts[b4+i2], 1);
  }
}

__global__ void scan_kernel(const int* __restrict__ counts, int* __restrict__ offsets,
                            int* __restrict__ cursors) {
  if (threadIdx.x == 0 && blockIdx.x == 0) {
    int s = 0;
    for (int e = 0; e < 8; ++e) { offsets[e] = s; s += counts[e]; cursors[e] = 0; }
    offsets[8] = s;
  }
}

__global__ void scatter_kernel(const int* __restrict__ eidx, const int* __restrict__ offsets,
                               int* __restrict__ cursors, int* __restrict__ list,
                               int* __restrict__ slot) {
  int t = blockIdx.x*256 + threadIdx.x;
  if (t < 1024) {
#pragma unroll
    for (int kk = 0; kk < 2; ++kk) {
      int e = eidx[t*2+kk];
      int pos = atomicAdd(&cursors[e], 1);
      int g = offsets[e] + pos;
      list[g] = t;
      slot[t*2+kk] = g;
    }
  }
}

__global__ void combine_kernel(const float* __restrict__ h2, const float* __restrict__ y,
                               const float* __restrict__ sdown, const int* __restrict__ slot,
                               const float* __restrict__ ew, float* __restrict__ out) {
  int i = blockIdx.x*256 + threadIdx.x;
  int t = i >> 11;
  int d = i & 2047;
  float rv = ew[t*2]   * y[(long)slot[t*2]  *2048 + d]
           + ew[t*2+1] * y[(long)slot[t*2+1]*2048 + d];
  out[i] = h2[i] + sdown[i] + 2.5f * rv;
}

extern "C" void kernel_launch(void* const* d_in, const int* in_sizes, int n_in,
                              void* d_out, int out_size, void* d_ws, size_t ws_size,
                              hipStream_t stream) {
  const float* hid  = (const float*)d_in[0];
  const float* ln1  = (const float*)d_in[1];
  const float* ln2  = (const float*)d_in[2];
  const float* wq   = (const float*)d_in[3];
  const float* wk   = (const float*)d_in[4];
  const float* wv   = (const float*)d_in[5];
  const float* wo   = (const float*)d_in[6];
  const float* gw   = (const float*)d_in[7];
  const float* gb   = (const float*)d_in[8];
  const float* wgat = (const float*)d_in[9];
  const float* wup  = (const float*)d_in[10];
  const float* wdn  = (const float*)d_in[11];
  const float* swg  = (const float*)d_in[12];
  const float* swu  = (const float*)d_in[13];
  const float* swd  = (const float*)d_in[14];
  float* out = (float*)d_out;
  char* ws = (char*)d_ws;

  float*  h2    = (float*)(ws + oH2);
  __bf16* xb2   = (__bf16*)(ws + oXB2);
  __bf16* wqkvT = (__bf16*)(ws + oWQKVT);   // f16 bits
  __bf16* woT   = (__bf16*)(ws + oWOT);     // f16 bits
  __bf16* xn1   = (__bf16*)(ws + oXN1);     // f16 bits
  float*  qkv   = (float*)(ws + oQKV);
  float*  scf   = (float*)(ws + oSCF);
  __bf16* qks   = (__bf16*)(ws + oQKS);
  __bf16* vtb   = (__bf16*)(ws + oVT);
  float*  att   = (float*)(ws + oATT);
  __bf16* pb    = (__bf16*)(ws + oPB);
  __bf16* wgut  = (__bf16*)(ws + oWGUT);
  __bf16* wdt   = (__bf16*)(ws + oWDT);
  __bf16* sgut  = (__bf16*)(ws + oSGUT);
  __bf16* sdt   = (__bf16*)(ws + oSDT);
  __bf16* hb    = (__bf16*)(ws + oHB);
  float*  ybuf  = (float*)(ws + oY);
  __bf16* shb   = (__bf16*)(ws + oSHB);
  float*  sdb   = (float*)(ws + oSDB);
  int*   eidx = (int*)(ws + oEIDX);
  float* ew   = (float*)(ws + oEW);
  int*   slot = (int*)(ws + oSLOT);
  int*   list = (int*)(ws + oLIST);
  int*   cnt  = (int*)(ws + oCNT);
  int*   offs = (int*)(ws + oOFF);
  int*   curs = (int*)(ws + oCUR);

  const long S22 = (long)2048*2048, S21 = (long)2048*1024;
  const long pQKS  = (oQKSL - oQKS) / 2;
  const long pVT   = 2*MB;
  const long pPB   = (oPBL2 - oPB) / 2;

  // --- attention weight transposes: f32 [D,N] -> f16 [N,D] (single plane) ---
  transpose_kernel<3><<<dim3(32,32,1), 256, 0, stream>>>(wq, wqkvT,          2048, 2048, 1, 0, 0, 0, 0);
  transpose_kernel<3><<<dim3(32,32,1), 256, 0, stream>>>(wk, wqkvT + S22,    2048, 2048, 1, 0, 0, 0, 0);
  transpose_kernel<3><<<dim3(32,32,1), 256, 0, stream>>>(wv, wqkvT + 2*S22,  2048, 2048, 1, 0, 0, 0, 0);
  transpose_kernel<3><<<dim3(32,32,1), 256, 0, stream>>>(wo, woT,            2048, 2048, 1, 0, 0, 0, 0);

  // --- attention ---
  rmsnorm_kernel<3><<<1024, 256, 0, stream>>>(hid, ln1, xn1, 0);

  // fused QKV (f16 single, 1-term MFMA): [1024,2048] x [6144,2048]^T -> qkv f32
  gemm_kernel<0, 3, false, false, false, 64, 128><<<dim3(48,16,1), 256, 0, stream>>>(
      xn1, wqkvT, qkv, nullptr, 1024, 6144, 2048, 2048, 2048, 6144,
      1, 0, 0, 0, 0, 0, 0, 0, 0, nullptr, nullptr, nullptr);

  // RoPE + split q,k -> qks hi/lo [1024,4096]  (bf16-split path unchanged)
  rope_split_kernel<<<4096, 256, 0, stream>>>(qkv, qks, pQKS);

  // V^T per (b,h): qkv v-part [512,128] -> vtb hi/lo [32][128][512]
  transpose_kernel<2><<<dim3(2,8,32), 256, 0, stream>>>(
      qkv + 4096, vtb, 6144, 512, 16, (long)512*6144, 128, (long)128*512, pVT);

  // scores = Q @ K^T (SP=2 bf16-split, causal tile-skip)
  gemm_kernel<0, 2, false, true, false, 64, 64><<<dim3(8,8,32), 256, 0, stream>>>(
      qks, qks + 2048, scf, nullptr, 512, 512, 128, 4096, 4096, 512,
      16, (long)512*4096, 128, (long)512*4096, 128, (long)16*512*512, (long)512*512,
      pQKS, pQKS, nullptr, nullptr, nullptr);

  // softmax -> P hi/lo
  softmax_kernel<<<16384, 256, 0, stream>>>(scf, pb, pPB);

  // attn = P @ V (SP=2 bf16-split, K-early-stop)
  gemm_kernel<0, 2, false, false, true, 64, 64><<<dim3(2,8,32), 256, 0, stream>>>(
      pb, vtb, att, nullptr, 512, 128, 512, 512, 512, 2048,
      16, (long)16*512*512, (long)512*512, (long)16*128*512, (long)128*512,
      (long)512*2048, 128, pPB, pVT, nullptr, nullptr, nullptr);

  // h2 = hidden + attn @ wo  (SP=4: A f32->f16 on-the-fly, B f16, 1-term)
  gemm_kernel<0, 4, true, false, false, 64, 64><<<dim3(32,16,1), 256, 0, stream>>>(
      att, woT, h2, hid, 1024, 2048, 2048, 2048, 2048, 2048,
      1, 0, 0, 0, 0, 0, 0, 0, 0, nullptr, nullptr, nullptr);

  // --- routing (rmsnorm2 fused: writes xb2) ---
  zero8_kernel<<<1, 64, 0, stream>>>(cnt);
  routing_kernel<<<1024, 256, 0, stream>>>(h2, ln2, gw, gb, xb2, eidx, ew, cnt);
  scan_kernel<<<1, 64, 0, stream>>>(cnt, offs, curs);
  scatter_kernel<<<4, 256, 0, stream>>>(eidx, offs, curs, list, slot);

  // --- MoE weight transposes (f32 -> bf16 single [N,K]) ---
  transpose_kernel<1><<<dim3(16,32,8), 256, 0, stream>>>(wgat, wgut,        1024, 2048, 1, S21, 0, S22, 0);
  transpose_kernel<1><<<dim3(16,32,8), 256, 0, stream>>>(wup,  wgut + S21,  1024, 2048, 1, S21, 0, S22, 0);
  transpose_kernel<1><<<dim3(32,16,8), 256, 0, stream>>>(wdn,  wdt,         2048, 1024, 1, S21, 0, S21, 0);
  transpose_kernel<1><<<dim3(16,32,1), 256, 0, stream>>>(swg,  sgut,        1024, 2048, 1, 0, 0, 0, 0);
  transpose_kernel<1><<<dim3(16,32,1), 256, 0, stream>>>(swu,  sgut + S21,  1024, 2048, 1, 0, 0, 0, 0);
  transpose_kernel<1><<<dim3(32,16,1), 256, 0, stream>>>(swd,  sdt,         2048, 1024, 1, 0, 0, 0, 0);

  // --- routed experts: fused gate|up|silu -> hb, then down ---
  gugemm_kernel<1><<<dim3(16,16,8), 256, 0, stream>>>(
      xb2, wgut, hb, 1024, 2048, 2048, 2048, S22, cnt, offs, list);
  gemm_kernel<2, 0, false, false, false, 64, 64><<<dim3(32,16,8), 256, 0, stream>>>(
      hb, wdt, ybuf, nullptr, 1024, 2048, 1024, 1024, 1024, 2048,
      1, 0, 0, S21, 0, 0, 0, 0, 0, cnt, offs, nullptr);

  // --- shared expert: fused gate|up|silu -> shb, then down ---
  gugemm_kernel<0><<<dim3(16,16,1), 256, 0, stream>>>(
      xb2, sgut, shb, 1024, 2048, 2048, 2048, 0, nullptr, nullptr, nullptr);
  gemm_kernel<0, 0, false, false, false, 64, 64><<<dim3(32,16,1), 256, 0, stream>>>(
      shb, sdt, sdb, nullptr, 1024, 2048, 1024, 1024, 1024, 2048,
      1, 0, 0, 0, 0, 0, 0, 0, 0, nullptr, nullptr, nullptr);

  // --- combine ---
  combine_kernel<<<8192, 256, 0, stream>>>(h2, ybuf, sdb, slot, ew, out);
}

// Round 7
// 650.712 us; speedup vs baseline: 1.1799x; 1.0850x over previous
//
#include <hip/hip_runtime.h>

typedef __bf16 bf16x4 __attribute__((ext_vector_type(4)));
typedef __bf16 bf16x8 __attribute__((ext_vector_type(8)));
typedef _Float16 f16x4 __attribute__((ext_vector_type(4)));
typedef _Float16 f16x8 __attribute__((ext_vector_type(8)));
typedef float  f32x4  __attribute__((ext_vector_type(4)));

#define THREADS 256
constexpr int BK = 32, BKP = 40;

// ---- workspace layout (bytes), total <=160 MB ----
constexpr size_t MB = 1024*1024;
// persistent
constexpr size_t oH2    = 0;            // f32 [1024,2048] 8MB
constexpr size_t oXB2   = 8*MB;         // bf16 [1024,2048] 4MB
constexpr size_t oRT    = 12*MB;        // routing scratch (1MB)
// attention phase
constexpr size_t oWQKVT = 16*MB;        // f16 [6144,2048] 24MB
constexpr size_t oWOT   = 64*MB;        // f16 [2048,2048] 8MB
constexpr size_t oXN1   = 80*MB;        // f16 [1024,2048] 4MB
constexpr size_t oQKV   = 88*MB;        // f32 [1024,6144] 24MB (dead after rope/VT)
constexpr size_t oSCF   = 112*MB;       // f32 [32,512,512] 32MB (dead after softmax)
constexpr size_t oQKS   = 144*MB;       // bf16 hi [1024,4096] 8MB
constexpr size_t oQKSL  = 152*MB;       // bf16 lo 8MB
// overlays (dead wqkvT after QKV gemm)
constexpr size_t oVT    = 16*MB;        // bf16 hi [32,128,512] 4MB
constexpr size_t oVTL   = 20*MB;        // bf16 lo 4MB
constexpr size_t oATT   = 24*MB;        // f32 [1024,2048] 8MB
constexpr size_t oPB    = 40*MB;        // bf16 hi [32,512,512] 16MB
constexpr size_t oPBL2  = 88*MB;        // bf16 lo [32,512,512] 16MB (over dead qkv)
// MoE phase (everything >=16MB dead after WO gemm)
constexpr size_t oWGUT  = 16*MB;        // bf16 [8,2048,2048] 64MB  (+ sgut right after)
constexpr size_t oSGUT  = 80*MB;        // bf16 [2048,2048] 8MB = wgut + 8*S22
constexpr size_t oWDT   = 88*MB;        // bf16 [8,2048,1024] 32MB (+ sdt right after)
constexpr size_t oSDT   = 120*MB;       // bf16 [2048,1024] 4MB = wdt + 8*S21
constexpr size_t oHBC   = 124*MB;       // bf16 [3072,1024] 6MB (routed slots 0..2047, shared 2048..3071)
constexpr size_t oYC    = 130*MB;       // f32 [3072,2048] 24MB (routed y slots | shared down)
// routing arrays
constexpr size_t oEIDX = oRT;
constexpr size_t oEW   = oRT + 8192;
constexpr size_t oSLOT = oRT + 16384;
constexpr size_t oLIST = oRT + 24576;
constexpr size_t oCNT  = oRT + 32768;
constexpr size_t oOFF  = oRT + 33024;
constexpr size_t oCUR  = oRT + 33280;

__device__ __forceinline__ bf16x8 bzero8() {
  bf16x8 z;
#pragma unroll
  for (int j = 0; j < 8; ++j) z[j] = (__bf16)0.f;
  return z;
}

// ---- 64x64 LDS tile transpose. OM: 1 = bf16, 2 = bf16 hi/lo planes, 3 = f16 ----
template<int OM>
__global__ void transpose_kernel(const float* __restrict__ in, __bf16* __restrict__ out,
                                 int ldin, int ldout, int zlo,
                                 long inBH, long inBL, long outB, long plane) {
  __shared__ float tile[64][65];
  int z = blockIdx.z;
  const float* inp = in + (long)(z / zlo) * inBH + (long)(z % zlo) * inBL;
  __bf16* outp = out + (long)z * outB;
  int r0 = blockIdx.y * 64, c0 = blockIdx.x * 64;
  int tid = threadIdx.x;
#pragma unroll
  for (int i = 0; i < 4; ++i) {
    int lin = tid + i * 256;
    int r = lin >> 4, c4 = (lin & 15) << 2;
    f32x4 v = *(const f32x4*)(inp + (long)(r0 + r) * ldin + c0 + c4);
    tile[r][c4] = v[0]; tile[r][c4+1] = v[1]; tile[r][c4+2] = v[2]; tile[r][c4+3] = v[3];
  }
  __syncthreads();
#pragma unroll
  for (int i = 0; i < 4; ++i) {
    int lin = tid + i * 256;
    int oR = lin >> 4, oC4 = (lin & 15) << 2;
    __bf16* dst = outp + (long)(c0 + oR) * ldout + r0 + oC4;
    if constexpr (OM == 3) {
      f16x4 hv;
#pragma unroll
      for (int j = 0; j < 4; ++j) hv[j] = (_Float16)tile[oC4 + j][oR];
      *reinterpret_cast<f16x4*>(dst) = hv;
    } else {
      bf16x4 hi, lo;
#pragma unroll
      for (int j = 0; j < 4; ++j) {
        float v = tile[oC4 + j][oR];
        hi[j] = (__bf16)v;
        if constexpr (OM == 2) lo[j] = (__bf16)(v - (float)hi[j]);
      }
      *(bf16x4*)dst = hi;
      if constexpr (OM == 2) *(bf16x4*)(dst + plane) = lo;
    }
  }
}

// MODE 0: batched strided; MODE 1: gathered A rows; MODE 2: dense A rows at offsets
// SP 0: single bf16 (1-term); SP 1: A f32->bf16split fly, B planes (3-term)
// SP 2: A+B pre-split planes (3-term); SP 3: f16 single; SP 4: A f32->f16 fly, B f16
// Single-LDS-buffer issue-early/write-late pipeline (T14).
template<int MODE, int SP, bool RESID, bool CAUSAL, bool KTRI, int TBM = 128, int TBN = 128>
__global__ __launch_bounds__(256, 2)
void gemm_kernel(const void* __restrict__ Av, const void* __restrict__ Bv, float* __restrict__ C,
                 const float* __restrict__ Rres,
                 int M, int N, int K, int lda, int ldb, int ldc,
                 int zlo, long aHi, long aLo, long bHi, long bLo, long cHi, long cLo,
                 long aPlane, long bPlane,
                 const int* __restrict__ counts, const int* __restrict__ offsets,
                 const int* __restrict__ gather) {
  const int n0 = blockIdx.x * TBN;
  const int m0 = blockIdx.y * TBM;
  const int z  = blockIdx.z;
  if (CAUSAL && n0 > m0) return;

  const float*  Af = (const float*)Av;
  const __bf16* Ah = (const __bf16*)Av;
  const __bf16* Bh = (const __bf16*)Bv;

  int mcount; int rowbase = 0;
  long aoff = 0, boff = 0, coff = 0;
  if constexpr (MODE == 0) {
    mcount = M;
    int zh = z / zlo, zl = z % zlo;
    aoff = (long)zh*aHi + (long)zl*aLo;
    boff = (long)zh*bHi + (long)zl*bLo;
    coff = (long)zh*cHi + (long)zl*cLo;
  } else {
    mcount = counts[z];
    rowbase = offsets[z];
    if (m0 >= mcount) return;
    boff = (long)z*bHi;
  }

  constexpr bool TRI  = (SP == 1 || SP == 2);
  constexpr bool F16  = (SP == 3 || SP == 4);
  constexpr bool AFLY = (SP == 1 || SP == 4);
  constexpr int ABUF = TBM*BKP;
  constexpr int BBUF = TBN*BKP;
  constexpr int WTM = TBM/2, WTN = TBN/2;
  constexpr int MI = WTM/16, MJ = WTN/16;
  __shared__ __align__(16) __bf16 As[(TRI?2:1)*ABUF];
  __shared__ __align__(16) __bf16 Bs[(TRI?2:1)*BBUF];

  const int tid = threadIdx.x;
  const int lane = tid & 63, wave = tid >> 6;
  const int wm = wave >> 1, wn = wave & 1;
  const int lq = lane >> 4, lr = lane & 15;

  int kend = K;
  if (KTRI) { int ke = m0 + TBM; kend = ke < K ? ke : K; }

  f32x4 acc[MI][MJ] = {};

  constexpr int NAF = AFLY ? TBM/32 : 1;
  constexpr int NAH = (!AFLY) ? TBM/64 : 1;
  constexpr int NB  = TBN/64;
  f32x4  arf[NAF];
  bf16x8 arh[NAH], arl[NAH];
  bf16x8 brh[NB],  brl[NB];

  auto loadAB = [&](int kk) {
    if constexpr (AFLY) {
#pragma unroll
      for (int it = 0; it < NAF; ++it) {
        int lin = tid + it*THREADS;
        int row = lin >> 3, c4 = (lin & 7) << 2;
        int gr = m0 + row;
        f32x4 zv; zv[0]=0.f; zv[1]=0.f; zv[2]=0.f; zv[3]=0.f;
        arf[it] = (gr < mcount) ? *(const f32x4*)(Af + aoff + (long)gr*lda + kk + c4) : zv;
      }
    } else {
#pragma unroll
      for (int it = 0; it < NAH; ++it) {
        int lin = tid + it*THREADS;
        int row = lin >> 2, c8 = (lin & 3) << 3;
        int gr = m0 + row;
        arh[it] = bzero8();
        if constexpr (SP == 2) arl[it] = bzero8();
        if (gr < mcount) {
          long arow;
          if constexpr (MODE == 1) arow = gather[rowbase + gr];
          else if constexpr (MODE == 2) arow = rowbase + gr;
          else arow = gr;
          const __bf16* p = Ah + aoff + arow*(long)lda + kk + c8;
          arh[it] = *(const bf16x8*)p;
          if constexpr (SP == 2) arl[it] = *(const bf16x8*)(p + aPlane);
        }
      }
    }
#pragma unroll
    for (int it = 0; it < NB; ++it) {
      int lin = tid + it*THREADS;
      int row = lin >> 2, c8 = (lin & 3) << 3;
      const __bf16* p = Bh + boff + (long)(n0+row)*ldb + kk + c8;
      brh[it] = *(const bf16x8*)p;
      if constexpr (TRI) brl[it] = *(const bf16x8*)(p + bPlane);
    }
  };

  auto writeAB = [&]() {
    if constexpr (AFLY) {
#pragma unroll
      for (int it = 0; it < NAF; ++it) {
        int lin = tid + it*THREADS;
        int row = lin >> 3, c4 = (lin & 7) << 2;
        if constexpr (SP == 4) {
          f16x4 hv;
#pragma unroll
          for (int j = 0; j < 4; ++j) hv[j] = (_Float16)arf[it][j];
          *reinterpret_cast<f16x4*>(As + row*BKP + c4) = hv;
        } else {
          bf16x4 hi, lo;
#pragma unroll
          for (int j = 0; j < 4; ++j) {
            hi[j] = (__bf16)arf[it][j];
            lo[j] = (__bf16)(arf[it][j] - (float)hi[j]);
          }
          *(bf16x4*)(As + row*BKP + c4) = hi;
          *(bf16x4*)(As + ABUF + row*BKP + c4) = lo;
        }
      }
    } else {
#pragma unroll
      for (int it = 0; it < NAH; ++it) {
        int lin = tid + it*THREADS;
        int row = lin >> 2, c8 = (lin & 3) << 3;
        *(bf16x8*)(As + row*BKP + c8) = arh[it];
        if constexpr (SP == 2) *(bf16x8*)(As + ABUF + row*BKP + c8) = arl[it];
      }
    }
#pragma unroll
    for (int it = 0; it < NB; ++it) {
      int lin = tid + it*THREADS;
      int row = lin >> 2, c8 = (lin & 3) << 3;
      *(bf16x8*)(Bs + row*BKP + c8) = brh[it];
      if constexpr (TRI) *(bf16x8*)(Bs + BBUF + row*BKP + c8) = brl[it];
    }
  };

  loadAB(0);
  writeAB();
  __syncthreads();

  for (int k0 = 0; k0 < kend; k0 += BK) {
    const bool hn = (k0 + BK < kend);
    if (hn) loadAB(k0 + BK);

    const __bf16* ap = As + (wm*WTM + lr)*BKP + lq*8;
    const __bf16* bp = Bs + (wn*WTN + lr)*BKP + lq*8;
    if constexpr (F16) {
      f16x8 fa[MI];
#pragma unroll
      for (int i = 0; i < MI; ++i)
        fa[i] = *reinterpret_cast<const f16x8*>(ap + i*16*BKP);
#pragma unroll
      for (int j = 0; j < MJ; ++j) {
        f16x8 fb = *reinterpret_cast<const f16x8*>(bp + j*16*BKP);
#pragma unroll
        for (int i = 0; i < MI; ++i)
          acc[i][j] = __builtin_amdgcn_mfma_f32_16x16x32_f16(fa[i], fb, acc[i][j], 0, 0, 0);
      }
    } else {
      bf16x8 fa[MI], fal[MI];
#pragma unroll
      for (int i = 0; i < MI; ++i) {
        fa[i] = *(const bf16x8*)(ap + i*16*BKP);
        if constexpr (TRI) fal[i] = *(const bf16x8*)(ap + ABUF + i*16*BKP);
      }
#pragma unroll
      for (int j = 0; j < MJ; ++j) {
        bf16x8 fb = *(const bf16x8*)(bp + j*16*BKP);
        if constexpr (TRI) {
          bf16x8 fbl = *(const bf16x8*)(bp + BBUF + j*16*BKP);
#pragma unroll
          for (int i = 0; i < MI; ++i) {
            acc[i][j] = __builtin_amdgcn_mfma_f32_16x16x32_bf16(fa[i],  fbl, acc[i][j], 0, 0, 0);
            acc[i][j] = __builtin_amdgcn_mfma_f32_16x16x32_bf16(fal[i], fb,  acc[i][j], 0, 0, 0);
            acc[i][j] = __builtin_amdgcn_mfma_f32_16x16x32_bf16(fa[i],  fb,  acc[i][j], 0, 0, 0);
          }
        } else {
#pragma unroll
          for (int i = 0; i < MI; ++i)
            acc[i][j] = __builtin_amdgcn_mfma_f32_16x16x32_bf16(fa[i], fb, acc[i][j], 0, 0, 0);
        }
      }
    }

    if (hn) {
      __syncthreads();
      writeAB();
      __syncthreads();
    }
  }

#pragma unroll
  for (int i = 0; i < MI; ++i) {
#pragma unroll
    for (int rg = 0; rg < 4; ++rg) {
      int lrow = wm*WTM + i*16 + lq*4 + rg;
      int gr = m0 + lrow;
      if (gr < mcount) {
        long crow = coff + (long)(rowbase + gr)*ldc;
#pragma unroll
        for (int j = 0; j < MJ; ++j) {
          int col = n0 + wn*WTN + j*16 + lr;
          float val = acc[i][j][rg];
          if constexpr (RESID) val += Rres[(long)gr*ldc + col];
          C[crow + col] = val;
        }
      }
    }
  }
}

// Merged gate/up gemm + silu*mul epilogue over 9 "experts" (z==8 = shared).
// A bf16 [1024,2048] tokens. B = wgut (z<8) / sgut (z==8, = wgut+8*S22).
// O bf16 [3072,1024]: row = offsets[z]+gr (routed slots 0..2047, shared 2048..3071).
// BK=64 for latency amortization.
__global__ __launch_bounds__(256, 2)
void gugemm_kernel(const __bf16* __restrict__ A, const __bf16* __restrict__ B,
                   __bf16* __restrict__ O, int K, int lda, int ldb, long bHi,
                   const int* __restrict__ counts, const int* __restrict__ offsets,
                   const int* __restrict__ gather) {
  constexpr int BKg = 64, BKP2 = 72;
  const int n0 = blockIdx.x * 64;
  const int m0 = blockIdx.y * 64;
  const int z  = blockIdx.z;

  const int mcount = counts[z];
  const int rowbase = offsets[z];
  if (m0 >= mcount) return;
  const long boff = (long)z*bHi;
  const bool shared = (z == 8);

  constexpr int TBUF = 64*BKP2;
  __shared__ __align__(16) __bf16 As[TBUF];
  __shared__ __align__(16) __bf16 Bg[TBUF];
  __shared__ __align__(16) __bf16 Bu[TBUF];

  const int tid = threadIdx.x;
  const int lane = tid & 63, wave = tid >> 6;
  const int wm = wave >> 1, wn = wave & 1;
  const int lq = lane >> 4, lr = lane & 15;

  f32x4 accG[2][2] = {}, accU[2][2] = {};

  // staging: 2 row-chunks per thread per stream (64 rows x 64 cols bf16)
  const int r0 = tid >> 3;              // 0..31
  const int c8 = (tid & 7) << 3;        // 0..56
  long aB0, aB1; bool aOK0, aOK1;
  {
    int g0 = m0 + r0, g1 = m0 + r0 + 32;
    aOK0 = g0 < mcount; aOK1 = g1 < mcount;
    long ar0 = 0, ar1 = 0;
    if (aOK0) ar0 = shared ? g0 : gather[rowbase + g0];
    if (aOK1) ar1 = shared ? g1 : gather[rowbase + g1];
    aB0 = ar0*(long)lda; aB1 = ar1*(long)lda;
  }
  const long gB0 = boff + (long)(n0 + r0)*ldb;
  const long gB1 = boff + (long)(n0 + r0 + 32)*ldb;
  const long uB0 = boff + (long)(1024 + n0 + r0)*ldb;
  const long uB1 = boff + (long)(1024 + n0 + r0 + 32)*ldb;

  bf16x8 ar0v, ar1v, bg0, bg1, bu0, bu1;
  auto loadAB = [&](int kk) {
    ar0v = aOK0 ? *(const bf16x8*)(A + aB0 + kk + c8) : bzero8();
    ar1v = aOK1 ? *(const bf16x8*)(A + aB1 + kk + c8) : bzero8();
    bg0 = *(const bf16x8*)(B + gB0 + kk + c8);
    bg1 = *(const bf16x8*)(B + gB1 + kk + c8);
    bu0 = *(const bf16x8*)(B + uB0 + kk + c8);
    bu1 = *(const bf16x8*)(B + uB1 + kk + c8);
  };
  auto writeAB = [&]() {
    *(bf16x8*)(As + r0*BKP2 + c8) = ar0v;
    *(bf16x8*)(As + (r0+32)*BKP2 + c8) = ar1v;
    *(bf16x8*)(Bg + r0*BKP2 + c8) = bg0;
    *(bf16x8*)(Bg + (r0+32)*BKP2 + c8) = bg1;
    *(bf16x8*)(Bu + r0*BKP2 + c8) = bu0;
    *(bf16x8*)(Bu + (r0+32)*BKP2 + c8) = bu1;
  };

  loadAB(0);
  writeAB();
  __syncthreads();

  for (int k0 = 0; k0 < K; k0 += BKg) {
    const bool hn = (k0 + BKg < K);
    if (hn) loadAB(k0 + BKg);

    const __bf16* ap  = As + (wm*32 + lr)*BKP2 + lq*8;
    const __bf16* bgp = Bg + (wn*32 + lr)*BKP2 + lq*8;
    const __bf16* bup = Bu + (wn*32 + lr)*BKP2 + lq*8;
#pragma unroll
    for (int ks = 0; ks < BKg; ks += 32) {
      bf16x8 fa[2];
      fa[0] = *(const bf16x8*)(ap + ks);
      fa[1] = *(const bf16x8*)(ap + 16*BKP2 + ks);
#pragma unroll
      for (int j = 0; j < 2; ++j) {
        bf16x8 fg = *(const bf16x8*)(bgp + j*16*BKP2 + ks);
        bf16x8 fu = *(const bf16x8*)(bup + j*16*BKP2 + ks);
#pragma unroll
        for (int i = 0; i < 2; ++i) {
          accG[i][j] = __builtin_amdgcn_mfma_f32_16x16x32_bf16(fa[i], fg, accG[i][j], 0, 0, 0);
          accU[i][j] = __builtin_amdgcn_mfma_f32_16x16x32_bf16(fa[i], fu, accU[i][j], 0, 0, 0);
        }
      }
    }

    if (hn) {
      __syncthreads();
      writeAB();
      __syncthreads();
    }
  }

  // epilogue: silu(gate)*up -> bf16
#pragma unroll
  for (int i = 0; i < 2; ++i) {
#pragma unroll
    for (int rg = 0; rg < 4; ++rg) {
      int lrow = wm*32 + i*16 + lq*4 + rg;
      int gr = m0 + lrow;
      if (gr < mcount) {
        long orow = (long)(rowbase + gr)*1024;
#pragma unroll
        for (int j = 0; j < 2; ++j) {
          int col = n0 + wn*32 + j*16 + lr;
          float g = accG[i][j][rg], u = accU[i][j][rg];
          float val = (g / (1.f + expf(-g))) * u;
          O[orow + col] = (__bf16)val;
        }
      }
    }
  }
}

// OM 1: bf16 out; OM 2: bf16 hi/lo planes; OM 3: f16 out
template<int OM>
__global__ void rmsnorm_kernel(const float* __restrict__ x, const float* __restrict__ w,
                               __bf16* __restrict__ out, long plane) {
  const int row = blockIdx.x;
  const float* xr = x + (long)row * 2048;
  float ss = 0.f;
  for (int d = threadIdx.x; d < 2048; d += 256) { float v = xr[d]; ss += v*v; }
  __shared__ float red[4];
  int lane = threadIdx.x & 63, wave = threadIdx.x >> 6;
#pragma unroll
  for (int off = 32; off; off >>= 1) ss += __shfl_down(ss, off, 64);
  if (lane == 0) red[wave] = ss;
  __syncthreads();
  float tot = red[0] + red[1] + red[2] + red[3];
  float rs = rsqrtf(tot * (1.f/2048.f) + 1e-6f);
  __bf16* orow = out + (long)row * 2048;
  for (int d = threadIdx.x; d < 2048; d += 256) {
    float v = xr[d]*rs*w[d];
    if constexpr (OM == 3) {
      ((_Float16*)orow)[d] = (_Float16)v;
    } else {
      __bf16 h = (__bf16)v;
      orow[d] = h;
      if constexpr (OM == 2) orow[d + plane] = (__bf16)(v - (float)h);
    }
  }
}

// RoPE q,k from qkv f32 [1024,6144] -> rotated hi/lo bf16 [1024,4096]
__global__ void rope_split_kernel(const float* __restrict__ qkv, __bf16* __restrict__ o, long plane) {
  int tid = blockIdx.x*256 + threadIdx.x;
  int i = tid & 63;
  int th = tid >> 6;
  int h = th & 15;
  int t = th >> 4;
  int s = t & 511;
  long ib = (long)t*6144 + h*128;
  long ob = (long)t*4096 + h*128;
  float inv = 1.f / powf(10000.f, (float)i * (1.f/64.f));
  float ang = (float)s * inv;
  float c = cosf(ang), sn = sinf(ang);
  float q1 = qkv[ib+i], q2 = qkv[ib+64+i];
  float r1 = q1*c - q2*sn, r2 = q2*c + q1*sn;
  __bf16 h1 = (__bf16)r1, h2v = (__bf16)r2;
  o[ob+i] = h1;            o[ob+i+plane] = (__bf16)(r1 - (float)h1);
  o[ob+64+i] = h2v;        o[ob+64+i+plane] = (__bf16)(r2 - (float)h2v);
  float k1 = qkv[ib+2048+i], k2 = qkv[ib+2048+64+i];
  float s1 = k1*c - k2*sn, s2 = k2*c + k1*sn;
  __bf16 g1 = (__bf16)s1, g2 = (__bf16)s2;
  o[ob+2048+i] = g1;       o[ob+2048+i+plane] = (__bf16)(s1 - (float)g1);
  o[ob+2048+64+i] = g2;    o[ob+2048+64+i+plane] = (__bf16)(s2 - (float)g2);
}

// causal softmax: scf f32 -> P hi/lo bf16
__global__ void softmax_kernel(const float* __restrict__ sc, __bf16* __restrict__ p, long plane) {
  int r = blockIdx.x & 511;
  long bh = blockIdx.x >> 9;
  const float scale = 0.08838834764831845f;   // 1/sqrt(128)
  long base = (bh*512 + r)*512;
  int c0 = threadIdx.x, c1 = threadIdx.x + 256;
  float v0 = (c0 <= r) ? sc[base+c0]*scale : -3.0e38f;
  float v1 = (c1 <= r) ? sc[base+c1]*scale : -3.0e38f;
  float m = fmaxf(v0, v1);
  __shared__ float red[4];
  int lane = threadIdx.x & 63, wave = threadIdx.x >> 6;
#pragma unroll
  for (int off = 32; off; off >>= 1) m = fmaxf(m, __shfl_xor(m, off, 64));
  if (lane == 0) red[wave] = m;
  __syncthreads();
  m = fmaxf(fmaxf(red[0], red[1]), fmaxf(red[2], red[3]));
  __syncthreads();
  float e0 = (c0 <= r) ? expf(v0 - m) : 0.f;
  float e1 = (c1 <= r) ? expf(v1 - m) : 0.f;
  float s = e0 + e1;
#pragma unroll
  for (int off = 32; off; off >>= 1) s += __shfl_xor(s, off, 64);
  if (lane == 0) red[wave] = s;
  __syncthreads();
  s = red[0] + red[1] + red[2] + red[3];
  float inv = 1.f / s;
  float p0 = e0*inv, p1 = e1*inv;
  __bf16 h0 = (__bf16)p0, h1 = (__bf16)p1;
  p[base+c0] = h0; p[base+c0+plane] = (__bf16)(p0 - (float)h0);
  p[base+c1] = h1; p[base+c1+plane] = (__bf16)(p1 - (float)h1);
}

__global__ void zero8_kernel(int* c) { if (threadIdx.x < 8) c[threadIdx.x] = 0; }

// routing + fused rmsnorm2 (writes xb2)
__global__ void routing_kernel(const float* __restrict__ h2, const float* __restrict__ ln2w,
                               const float* __restrict__ gw, const float* __restrict__ gb,
                               __bf16* __restrict__ xb2,
                               int* __restrict__ eidx, float* __restrict__ ew,
                               int* __restrict__ counts) {
  int t = blockIdx.x;
  const float* xr = h2 + (long)t*2048;
  int lane = threadIdx.x & 63, wave = threadIdx.x >> 6;
  float ss = 0.f;
  for (int d = threadIdx.x; d < 2048; d += 256) { float v = xr[d]; ss += v*v; }
  __shared__ float red[4];
#pragma unroll
  for (int off = 32; off; off >>= 1) ss += __shfl_down(ss, off, 64);
  if (lane == 0) red[wave] = ss;
  __syncthreads();
  float rs = rsqrtf((red[0]+red[1]+red[2]+red[3]) * (1.f/2048.f) + 1e-6f);
  __bf16* xrow = xb2 + (long)t*2048;
  for (int d = threadIdx.x; d < 2048; d += 256) xrow[d] = (__bf16)(xr[d]*rs*ln2w[d]);
  __shared__ float lg[8];
  for (int e = wave; e < 8; e += 4) {
    const float* wr = gw + (long)e*2048;
    float acc = 0.f;
    for (int d = lane; d < 2048; d += 64) acc += (xr[d]*rs*ln2w[d]) * wr[d];
#pragma unroll
    for (int off = 32; off; off >>= 1) acc += __shfl_down(acc, off, 64);
    if (lane == 0) lg[e] = acc;
  }
  __syncthreads();
  if (threadIdx.x == 0) {
    float sg[8], sc[8];
#pragma unroll
    for (int e = 0; e < 8; ++e) { sg[e] = 1.f/(1.f+expf(-lg[e])); sc[e] = sg[e] + gb[e]; }
    float gs[2];
#pragma unroll
    for (int g = 0; g < 2; ++g) {
      float m1 = -3e38f, m2 = -3e38f;
#pragma unroll
      for (int j = 0; j < 4; ++j) {
        float v = sc[4*g+j];
        if (v > m1) { m2 = m1; m1 = v; } else if (v > m2) m2 = v;
      }
      gs[g] = m1 + m2;
    }
    int b4 = (gs[1] > gs[0]) ? 4 : 0;
    int i1 = 0; float v1 = -3e38f;
#pragma unroll
    for (int j = 0; j < 4; ++j) if (sc[b4+j] > v1) { v1 = sc[b4+j]; i1 = j; }
    int i2 = -1; float v2 = -3e38f;
#pragma unroll
    for (int j = 0; j < 4; ++j) if (j != i1 && sc[b4+j] > v2) { v2 = sc[b4+j]; i2 = j; }
    float w1 = sg[b4+i1], w2 = sg[b4+i2], s = w1 + w2;
    eidx[t*2] = b4+i1; eidx[t*2+1] = b4+i2;
    ew[t*2] = w1/s;    ew[t*2+1] = w2/s;
    atomicAdd(&counts[b4+i1], 1); atomicAdd(&counts[b4+i2], 1);
  }
}

__global__ void scan_kernel(const int* __restrict__ counts_in, int* __restrict__ counts,
                            int* __restrict__ offsets, int* __restrict__ cursors) {
  if (threadIdx.x == 0 && blockIdx.x == 0) {
    int s = 0;
    for (int e = 0; e < 8; ++e) { offsets[e] = s; s += counts[e]; cursors[e] = 0; }
    offsets[8] = s;        // = 2048: shared rows start here
    counts[8]  = 1024;     // shared "expert" processes all tokens
  }
}

__global__ void scatter_kernel(const int* __restrict__ eidx, const int* __restrict__ offsets,
                               int* __restrict__ cursors, int* __restrict__ list,
                               int* __restrict__ slot) {
  int t = blockIdx.x*256 + threadIdx.x;
  if (t < 1024) {
#pragma unroll
    for (int kk = 0; kk < 2; ++kk) {
      int e = eidx[t*2+kk];
      int pos = atomicAdd(&cursors[e], 1);
      int g = offsets[e] + pos;
      list[g] = t;
      slot[t*2+kk] = g;
    }
  }
}

__global__ void combine_kernel(const float* __restrict__ h2, const float* __restrict__ y,
                               const int* __restrict__ slot,
                               const float* __restrict__ ew, float* __restrict__ out) {
  int i = blockIdx.x*256 + threadIdx.x;
  int t = i >> 11;
  int d = i & 2047;
  float rv = ew[t*2]   * y[(long)slot[t*2]  *2048 + d]
           + ew[t*2+1] * y[(long)slot[t*2+1]*2048 + d];
  float sh = y[(long)(2048 + t)*2048 + d];   // shared-down rows 2048..3071
  out[i] = h2[i] + sh + 2.5f * rv;
}

extern "C" void kernel_launch(void* const* d_in, const int* in_sizes, int n_in,
                              void* d_out, int out_size, void* d_ws, size_t ws_size,
                              hipStream_t stream) {
  const float* hid  = (const float*)d_in[0];
  const float* ln1  = (const float*)d_in[1];
  const float* ln2  = (const float*)d_in[2];
  const float* wq   = (const float*)d_in[3];
  const float* wk   = (const float*)d_in[4];
  const float* wv   = (const float*)d_in[5];
  const float* wo   = (const float*)d_in[6];
  const float* gw   = (const float*)d_in[7];
  const float* gb   = (const float*)d_in[8];
  const float* wgat = (const float*)d_in[9];
  const float* wup  = (const float*)d_in[10];
  const float* wdn  = (const float*)d_in[11];
  const float* swg  = (const float*)d_in[12];
  const float* swu  = (const float*)d_in[13];
  const float* swd  = (const float*)d_in[14];
  float* out = (float*)d_out;
  char* ws = (char*)d_ws;

  float*  h2    = (float*)(ws + oH2);
  __bf16* xb2   = (__bf16*)(ws + oXB2);
  __bf16* wqkvT = (__bf16*)(ws + oWQKVT);   // f16 bits
  __bf16* woT   = (__bf16*)(ws + oWOT);     // f16 bits
  __bf16* xn1   = (__bf16*)(ws + oXN1);     // f16 bits
  float*  qkv   = (float*)(ws + oQKV);
  float*  scf   = (float*)(ws + oSCF);
  __bf16* qks   = (__bf16*)(ws + oQKS);
  __bf16* vtb   = (__bf16*)(ws + oVT);
  float*  att   = (float*)(ws + oATT);
  __bf16* pb    = (__bf16*)(ws + oPB);
  __bf16* wgut  = (__bf16*)(ws + oWGUT);
  __bf16* sgut  = (__bf16*)(ws + oSGUT);    // = wgut + 8*S22
  __bf16* wdt   = (__bf16*)(ws + oWDT);
  __bf16* sdt   = (__bf16*)(ws + oSDT);     // = wdt + 8*S21
  __bf16* hbc   = (__bf16*)(ws + oHBC);
  float*  ybc   = (float*)(ws + oYC);
  int*   eidx = (int*)(ws + oEIDX);
  float* ew   = (float*)(ws + oEW);
  int*   slot = (int*)(ws + oSLOT);
  int*   list = (int*)(ws + oLIST);
  int*   cnt  = (int*)(ws + oCNT);
  int*   offs = (int*)(ws + oOFF);
  int*   curs = (int*)(ws + oCUR);

  const long S22 = (long)2048*2048, S21 = (long)2048*1024;
  const long pQKS  = (oQKSL - oQKS) / 2;
  const long pVT   = 2*MB;
  const long pPB   = (oPBL2 - oPB) / 2;

  // --- attention weight transposes: f32 [D,N] -> f16 [N,D] ---
  transpose_kernel<3><<<dim3(32,32,1), 256, 0, stream>>>(wq, wqkvT,          2048, 2048, 1, 0, 0, 0, 0);
  transpose_kernel<3><<<dim3(32,32,1), 256, 0, stream>>>(wk, wqkvT + S22,    2048, 2048, 1, 0, 0, 0, 0);
  transpose_kernel<3><<<dim3(32,32,1), 256, 0, stream>>>(wv, wqkvT + 2*S22,  2048, 2048, 1, 0, 0, 0, 0);
  transpose_kernel<3><<<dim3(32,32,1), 256, 0, stream>>>(wo, woT,            2048, 2048, 1, 0, 0, 0, 0);

  // --- attention ---
  rmsnorm_kernel<3><<<1024, 256, 0, stream>>>(hid, ln1, xn1, 0);

  gemm_kernel<0, 3, false, false, false, 64, 128><<<dim3(48,16,1), 256, 0, stream>>>(
      xn1, wqkvT, qkv, nullptr, 1024, 6144, 2048, 2048, 2048, 6144,
      1, 0, 0, 0, 0, 0, 0, 0, 0, nullptr, nullptr, nullptr);

  rope_split_kernel<<<4096, 256, 0, stream>>>(qkv, qks, pQKS);

  transpose_kernel<2><<<dim3(2,8,32), 256, 0, stream>>>(
      qkv + 4096, vtb, 6144, 512, 16, (long)512*6144, 128, (long)128*512, pVT);

  gemm_kernel<0, 2, false, true, false, 64, 64><<<dim3(8,8,32), 256, 0, stream>>>(
      qks, qks + 2048, scf, nullptr, 512, 512, 128, 4096, 4096, 512,
      16, (long)512*4096, 128, (long)512*4096, 128, (long)16*512*512, (long)512*512,
      pQKS, pQKS, nullptr, nullptr, nullptr);

  softmax_kernel<<<16384, 256, 0, stream>>>(scf, pb, pPB);

  gemm_kernel<0, 2, false, false, true, 64, 64><<<dim3(2,8,32), 256, 0, stream>>>(
      pb, vtb, att, nullptr, 512, 128, 512, 512, 512, 2048,
      16, (long)16*512*512, (long)512*512, (long)16*128*512, (long)128*512,
      (long)512*2048, 128, pPB, pVT, nullptr, nullptr, nullptr);

  gemm_kernel<0, 4, true, false, false, 64, 64><<<dim3(32,16,1), 256, 0, stream>>>(
      att, woT, h2, hid, 1024, 2048, 2048, 2048, 2048, 2048,
      1, 0, 0, 0, 0, 0, 0, 0, 0, nullptr, nullptr, nullptr);

  // --- routing (rmsnorm2 fused: writes xb2) ---
  zero8_kernel<<<1, 64, 0, stream>>>(cnt);
  routing_kernel<<<1024, 256, 0, stream>>>(h2, ln2, gw, gb, xb2, eidx, ew, cnt);
  scan_kernel<<<1, 64, 0, stream>>>(cnt, cnt, offs, curs);
  scatter_kernel<<<4, 256, 0, stream>>>(eidx, offs, curs, list, slot);

  // --- MoE weight transposes (f32 -> bf16 single [N,K]) ---
  transpose_kernel<1><<<dim3(16,32,8), 256, 0, stream>>>(wgat, wgut,        1024, 2048, 1, S21, 0, S22, 0);
  transpose_kernel<1><<<dim3(16,32,8), 256, 0, stream>>>(wup,  wgut + S21,  1024, 2048, 1, S21, 0, S22, 0);
  transpose_kernel<1><<<dim3(32,16,8), 256, 0, stream>>>(wdn,  wdt,         2048, 1024, 1, S21, 0, S21, 0);
  transpose_kernel<1><<<dim3(16,32,1), 256, 0, stream>>>(swg,  sgut,        1024, 2048, 1, 0, 0, 0, 0);
  transpose_kernel<1><<<dim3(16,32,1), 256, 0, stream>>>(swu,  sgut + S21,  1024, 2048, 1, 0, 0, 0, 0);
  transpose_kernel<1><<<dim3(32,16,1), 256, 0, stream>>>(swd,  sdt,         2048, 1024, 1, 0, 0, 0, 0);

  // --- merged experts (routed z=0..7 + shared z=8): gate|up|silu -> hbc, then down -> ybc ---
  gugemm_kernel<<<dim3(16,16,9), 256, 0, stream>>>(
      xb2, wgut, hbc, 2048, 2048, 2048, S22, cnt, offs, list);
  gemm_kernel<2, 0, false, false, false, 64, 64><<<dim3(32,16,9), 256, 0, stream>>>(
      hbc, wdt, ybc, nullptr, 1024, 2048, 1024, 1024, 1024, 2048,
      1, 0, 0, S21, 0, 0, 0, 0, 0, cnt, offs, nullptr);

  // --- combine (shared-down rows live at ybc[2048..3071]) ---
  combine_kernel<<<8192, 256, 0, stream>>>(h2, ybc, slot, ew, out);
}